// Round 4
// baseline (360.079 us; speedup 1.0000x reference)
//
#include <hip/hip_runtime.h>
#include <hip/hip_bf16.h>
#include <hip/hip_cooperative_groups.h>
#include <math.h>

#define NPTS 4096
#define FIN 512
#define FOUT 64

namespace cg = cooperative_groups;

typedef __attribute__((ext_vector_type(8))) short bf16x8;
typedef __attribute__((ext_vector_type(4))) float f32x4;

static __device__ __forceinline__ unsigned short bfbits(float x) {
  __hip_bfloat16 b = __float2bfloat16(x);
  return *reinterpret_cast<unsigned short*>(&b);
}

static __device__ __forceinline__ float wsum64(float v) {
  #pragma unroll
  for (int mm = 1; mm < 64; mm <<= 1) v += __shfl_xor(v, mm);
  return v;
}

// ---------------- prep: bf16 copy of h, row norms, init m1, Wh = h@W ----------------
__global__ __launch_bounds__(256) void k_prep(const float* __restrict__ h,
    const float* __restrict__ W, __hip_bfloat16* __restrict__ xb,
    float* __restrict__ sq, int* __restrict__ m1, float* __restrict__ Wh) {
  __shared__ float hs[4][512];
  int t = threadIdx.x, lane = t & 63, wid = t >> 6;
  int row = blockIdx.x * 4 + wid;
  const float4* hr = (const float4*)(h + (size_t)row * FIN);
  float4 a = hr[lane], b = hr[64 + lane];
  ushort4 pa = { bfbits(a.x), bfbits(a.y), bfbits(a.z), bfbits(a.w) };
  ushort4 pb = { bfbits(b.x), bfbits(b.y), bfbits(b.z), bfbits(b.w) };
  *(ushort4*)(xb + (size_t)row * FIN + 4 * lane) = pa;
  *(ushort4*)(xb + (size_t)row * FIN + 256 + 4 * lane) = pb;
  float s = a.x*a.x + a.y*a.y + a.z*a.z + a.w*a.w
          + b.x*b.x + b.y*b.y + b.z*b.z + b.w*b.w;
  s = wsum64(s);
  if (lane == 0) { sq[row] = s; m1[row] = 0x7F800000; }
  *(float4*)&hs[wid][4 * lane] = a;
  *(float4*)&hs[wid][256 + 4 * lane] = b;
  __syncthreads();
  float a0 = 0.f, a1 = 0.f, a2 = 0.f, a3 = 0.f;
  #pragma unroll 2
  for (int k = 0; k < 512; k += 4) {
    a0 = fmaf(hs[wid][k + 0], W[(k + 0) * FOUT + lane], a0);
    a1 = fmaf(hs[wid][k + 1], W[(k + 1) * FOUT + lane], a1);
    a2 = fmaf(hs[wid][k + 2], W[(k + 2) * FOUT + lane], a2);
    a3 = fmaf(hs[wid][k + 3], W[(k + 3) * FOUT + lane], a3);
  }
  Wh[(size_t)row * FOUT + lane] = (a0 + a1) + (a2 + a3);
}

// ---------------- transpose Wh -> WhbT (bf16, [64][4096]) ----------------
__global__ __launch_bounds__(256) void k_tr(const float* __restrict__ Wh,
    __hip_bfloat16* __restrict__ WhbT) {
  __shared__ __hip_bfloat16 tT[64][264];
  int t = threadIdx.x;
  int kbase = blockIdx.x * 256;
  for (int rep = 0; rep < 64; ++rep) {
    int idx = t + rep * 256;
    int k = idx >> 6, n = idx & 63;
    tT[n][k] = __float2bfloat16(Wh[(size_t)(kbase + k) * FOUT + n]);
  }
  __syncthreads();
  int n = t >> 2, kq = t & 3;
  #pragma unroll
  for (int rep = 0; rep < 8; ++rep) {
    int kk = kq * 64 + rep * 8;
    bf16x8 v = *(const bf16x8*)&tT[n][kk];
    *(bf16x8*)(WhbT + (size_t)n * NPTS + kbase + kk) = v;
  }
}

// ---------------- Gram + per-row NN-min: LDS-staged MFMA, triangular grid ----------------
__global__ __launch_bounds__(256) void k_gram2(const __hip_bfloat16* __restrict__ xb,
    const float* __restrict__ sq, int* __restrict__ m1) {
  int b = blockIdx.x, I = 0;
  while (b >= 32 - I) { b -= 32 - I; ++I; }
  int J = I + b;
  int tid = threadIdx.x, lane = tid & 63, wid = tid >> 6;

  __shared__ __align__(16) __hip_bfloat16 As[128 * 64];
  __shared__ __align__(16) __hip_bfloat16 Bs[128 * 64];

  int R0 = I * 128, C0 = J * 128;
  int rowBase = (wid >> 1) * 64;
  int colBase = (wid & 1) * 64;
  int lrow = lane & 15, hi = lane >> 4, rsub = hi * 4;

  f32x4 acc[4][4];
  #pragma unroll
  for (int p = 0; p < 4; ++p)
    #pragma unroll
    for (int q = 0; q < 4; ++q)
      acc[p][q] = (f32x4){0.f, 0.f, 0.f, 0.f};

  int srow = lane >> 3;
  int scol = ((lane & 7) ^ srow) * 8;
  const __hip_bfloat16* gA = xb + (size_t)(R0 + wid * 32 + srow) * FIN + scol;
  const __hip_bfloat16* gB = xb + (size_t)(C0 + wid * 32 + srow) * FIN + scol;
  char* lA = (char*)As + wid * 4096;
  char* lB = (char*)Bs + wid * 4096;
  int rdswz = (lrow & 7) << 4;

  for (int kt = 0; kt < 8; ++kt) {
    int K0 = kt * 64;
    #pragma unroll
    for (int j = 0; j < 4; ++j) {
      __builtin_amdgcn_global_load_lds(
          (const __attribute__((address_space(1))) unsigned int*)(gA + (size_t)(8 * j) * FIN + K0),
          (__attribute__((address_space(3))) unsigned int*)(lA + j * 1024), 16, 0, 0);
      __builtin_amdgcn_global_load_lds(
          (const __attribute__((address_space(1))) unsigned int*)(gB + (size_t)(8 * j) * FIN + K0),
          (__attribute__((address_space(3))) unsigned int*)(lB + j * 1024), 16, 0, 0);
    }
    __syncthreads();
    #pragma unroll
    for (int s = 0; s < 2; ++s) {
      int k0b = s * 64;
      bf16x8 av[4], bw[4];
      #pragma unroll
      for (int f = 0; f < 4; ++f) {
        int arow = rowBase + f * 16 + lrow;
        av[f] = *(const bf16x8*)((const char*)As + arow * 128 + ((k0b + hi * 16) ^ rdswz));
        int brow = colBase + f * 16 + lrow;
        bw[f] = *(const bf16x8*)((const char*)Bs + brow * 128 + ((k0b + hi * 16) ^ rdswz));
      }
      #pragma unroll
      for (int fi = 0; fi < 4; ++fi)
        #pragma unroll
        for (int fj = 0; fj < 4; ++fj)
          acc[fi][fj] = __builtin_amdgcn_mfma_f32_16x16x32_bf16(av[fi], bw[fj], acc[fi][fj], 0, 0, 0);
    }
    __syncthreads();
  }

  int rowBaseG = R0 + rowBase, colBaseG = C0 + colBase;
  float sqr[16], sqc4[4];
  #pragma unroll
  for (int fi = 0; fi < 4; ++fi)
    #pragma unroll
    for (int rg = 0; rg < 4; ++rg)
      sqr[fi * 4 + rg] = sq[rowBaseG + fi * 16 + rsub + rg];
  #pragma unroll
  for (int fj = 0; fj < 4; ++fj) sqc4[fj] = sq[colBaseG + fj * 16 + lrow];

  float rmin[16], cmin[4];
  #pragma unroll
  for (int q = 0; q < 16; ++q) rmin[q] = INFINITY;
  #pragma unroll
  for (int q = 0; q < 4; ++q) cmin[q] = INFINITY;

  #pragma unroll
  for (int fi = 0; fi < 4; ++fi)
    #pragma unroll
    for (int fj = 0; fj < 4; ++fj)
      #pragma unroll
      for (int rg = 0; rg < 4; ++rg) {
        int r = rowBaseG + fi * 16 + rsub + rg;
        int c = colBaseG + fj * 16 + lrow;
        float d2 = sqr[fi * 4 + rg] + sqc4[fj] - 2.f * acc[fi][fj][rg];
        if (r == c) d2 = INFINITY;
        rmin[fi * 4 + rg] = fminf(rmin[fi * 4 + rg], d2);
        cmin[fj] = fminf(cmin[fj], d2);
      }

  #pragma unroll
  for (int mm = 1; mm < 16; mm <<= 1) {
    #pragma unroll
    for (int q = 0; q < 16; ++q) rmin[q] = fminf(rmin[q], __shfl_xor(rmin[q], mm));
  }
  if ((lane & 15) == 0) {
    #pragma unroll
    for (int q = 0; q < 16; ++q) {
      int r = rowBaseG + (q >> 2) * 16 + rsub + (q & 3);
      atomicMin(&m1[r], __float_as_int(rmin[q]));
    }
  }
  if (I != J) {
    #pragma unroll
    for (int mm = 16; mm < 64; mm <<= 1) {
      #pragma unroll
      for (int q = 0; q < 4; ++q) cmin[q] = fminf(cmin[q], __shfl_xor(cmin[q], mm));
    }
    if ((lane >> 4) == 0) {
      #pragma unroll
      for (int q = 0; q < 4; ++q)
        atomicMin(&m1[colBaseG + q * 16 + lane], __float_as_int(cmin[q]));
    }
  }
}

// ---------------- cooperative: kmeans + d1val + dc/tm/kstar ----------------
// 64 blocks x 1024 threads; wave owns 4 rows in registers for the whole kernel.
__global__ __launch_bounds__(1024) void k_km(const float* __restrict__ h,
    const float* __restrict__ sq, const int* __restrict__ m1,
    const float* __restrict__ t2, const float* __restrict__ Wh,
    float* __restrict__ G, float* __restrict__ d1v,
    float* __restrict__ tmv, float* __restrict__ out) {
  cg::grid_group grid = cg::this_grid();
  extern __shared__ float smem[];
  float* wsum  = smem;                 // 16*1536
  float* cents = smem + 16 * 1536;     // 1536
  float* wcnt  = cents + 1536;         // 48
  float* mbv   = wcnt + 48;            // 16
  int*   mbi   = (int*)(mbv + 16);     // 16

  float* bvA    = G;
  int*   biA    = (int*)(G + 64);
  float* bvB    = G + 128;
  int*   biB    = (int*)(G + 192);
  float* dcpart = G + 256;             // 64
  float* tmpart = G + 320;             // 192
  float* kvp    = G + 512;             // 64
  int*   kip    = (int*)(G + 576);     // 64
  float* pcnts  = G + 640;             // 2*192
  float* psums  = G + 1024;            // 2*64*1536

  int t = threadIdx.x, lane = t & 63, wid = t >> 6;
  int b = blockIdx.x;
  int rbase = b * 64 + wid * 4;

  // rows resident in registers
  float rx[4][8], sqr[4];
  #pragma unroll
  for (int r = 0; r < 4; ++r) {
    const float4* xr = (const float4*)(h + (size_t)(rbase + r) * FIN);
    float4 a = xr[lane], bb = xr[64 + lane];
    rx[r][0]=a.x; rx[r][1]=a.y; rx[r][2]=a.z; rx[r][3]=a.w;
    rx[r][4]=bb.x; rx[r][5]=bb.y; rx[r][6]=bb.z; rx[r][7]=bb.w;
    sqr[r] = sq[rbase + r];
  }

  // phase-0 side jobs (dc / tm / kstar partials)
  if (wid == 0) {
    float v = sqrtf(fmaxf(__int_as_float(m1[b * 64 + lane]), 0.f));
    v = wsum64(v);
    if (lane == 0) dcpart[b] = v;
  } else if (wid == 1) {
    #pragma unroll
    for (int c = 0; c < 3; ++c) {
      float m = fabsf(t2[c * NPTS + b * 64 + lane]);
      #pragma unroll
      for (int mm = 1; mm < 64; mm <<= 1) m = fmaxf(m, __shfl_xor(m, mm));
      if (lane == 0) tmpart[b * 3 + c] = m;
    }
  } else if (wid == 2) {
    int k = b * 64 + lane;
    float v = t2[k] + t2[NPTS + k] + t2[2 * NPTS + k];
    int ki = k;
    #pragma unroll
    for (int mm = 1; mm < 64; mm <<= 1) {
      float ov = __shfl_xor(v, mm); int oi = __shfl_xor(ki, mm);
      if (ov < v || (ov == v && oi < ki)) { v = ov; ki = oi; }
    }
    if (lane == 0) { kvp[b] = v; kip[b] = ki; }
  }

  // ---- farthest-point pass A: c0 = h[0]
  float cr[8];
  {
    const float4* cp = (const float4*)h;
    float4 a = cp[lane], bb = cp[64 + lane];
    cr[0]=a.x; cr[1]=a.y; cr[2]=a.z; cr[3]=a.w; cr[4]=bb.x; cr[5]=bb.y; cr[6]=bb.z; cr[7]=bb.w;
  }
  float dloc[4];
  float bv = -1.f; int bi = 0;
  #pragma unroll
  for (int r = 0; r < 4; ++r) {
    float d = 0.f;
    #pragma unroll
    for (int q = 0; q < 8; ++q) { float df = rx[r][q] - cr[q]; d = fmaf(df, df, d); }
    d = wsum64(d);
    dloc[r] = d;
    if (d > bv) { bv = d; bi = rbase + r; }
  }
  if (lane == 0) { mbv[wid] = bv; mbi[wid] = bi; }
  __syncthreads();
  if (t == 0) {
    float vv = mbv[0]; int ii = mbi[0];
    for (int w = 1; w < 16; ++w)
      if (mbv[w] > vv || (mbv[w] == vv && mbi[w] < ii)) { vv = mbv[w]; ii = mbi[w]; }
    bvA[b] = vv; biA[b] = ii;
  }
  grid.sync();
  int b1;
  {
    float v = bvA[lane]; int i = biA[lane];
    #pragma unroll
    for (int mm = 1; mm < 64; mm <<= 1) {
      float ov = __shfl_xor(v, mm); int oi = __shfl_xor(i, mm);
      if (ov > v || (ov == v && oi < i)) { v = ov; i = oi; }
    }
    b1 = i;
  }
  // ---- pass B: c1 = h[b1]
  {
    const float4* cp = (const float4*)(h + (size_t)b1 * FIN);
    float4 a = cp[lane], bb = cp[64 + lane];
    cr[0]=a.x; cr[1]=a.y; cr[2]=a.z; cr[3]=a.w; cr[4]=bb.x; cr[5]=bb.y; cr[6]=bb.z; cr[7]=bb.w;
  }
  bv = -1.f; bi = 0;
  #pragma unroll
  for (int r = 0; r < 4; ++r) {
    float d = 0.f;
    #pragma unroll
    for (int q = 0; q < 8; ++q) { float df = rx[r][q] - cr[q]; d = fmaf(df, df, d); }
    d = wsum64(d);
    d = fminf(d, dloc[r]);
    dloc[r] = d;
    if (d > bv) { bv = d; bi = rbase + r; }
  }
  if (lane == 0) { mbv[wid] = bv; mbi[wid] = bi; }
  __syncthreads();
  if (t == 0) {
    float vv = mbv[0]; int ii = mbi[0];
    for (int w = 1; w < 16; ++w)
      if (mbv[w] > vv || (mbv[w] == vv && mbi[w] < ii)) { vv = mbv[w]; ii = mbi[w]; }
    bvB[b] = vv; biB[b] = ii;
  }
  grid.sync();
  int b2;
  {
    float v = bvB[lane]; int i = biB[lane];
    #pragma unroll
    for (int mm = 1; mm < 64; mm <<= 1) {
      float ov = __shfl_xor(v, mm); int oi = __shfl_xor(i, mm);
      if (ov > v || (ov == v && oi < i)) { v = ov; i = oi; }
    }
    b2 = i;
  }
  // init centers in LDS
  if (t < 512) {
    cents[t]        = h[t];
    cents[512 + t]  = h[(size_t)b1 * FIN + t];
    cents[1024 + t] = h[(size_t)b2 * FIN + t];
  }
  __syncthreads();

  float c0r[8], c1r[8], c2r[8];
  float sqc0, sqc1, sqc2;

  // ---- Lloyd x10 (1 grid sync per iter, redundant update, dbuf psums)
  for (int it = 0; it < 10; ++it) {
    {
      float4 a = *(const float4*)&cents[8 * lane], bb = *(const float4*)&cents[8 * lane + 4];
      c0r[0]=a.x;c0r[1]=a.y;c0r[2]=a.z;c0r[3]=a.w;c0r[4]=bb.x;c0r[5]=bb.y;c0r[6]=bb.z;c0r[7]=bb.w;
      a = *(const float4*)&cents[512 + 8 * lane]; bb = *(const float4*)&cents[512 + 8 * lane + 4];
      c1r[0]=a.x;c1r[1]=a.y;c1r[2]=a.z;c1r[3]=a.w;c1r[4]=bb.x;c1r[5]=bb.y;c1r[6]=bb.z;c1r[7]=bb.w;
      a = *(const float4*)&cents[1024 + 8 * lane]; bb = *(const float4*)&cents[1024 + 8 * lane + 4];
      c2r[0]=a.x;c2r[1]=a.y;c2r[2]=a.z;c2r[3]=a.w;c2r[4]=bb.x;c2r[5]=bb.y;c2r[6]=bb.z;c2r[7]=bb.w;
    }
    {
      float s0 = 0.f, s1 = 0.f, s2 = 0.f;
      #pragma unroll
      for (int q = 0; q < 8; ++q) {
        s0 = fmaf(c0r[q], c0r[q], s0); s1 = fmaf(c1r[q], c1r[q], s1); s2 = fmaf(c2r[q], c2r[q], s2);
      }
      sqc0 = wsum64(s0); sqc1 = wsum64(s1); sqc2 = wsum64(s2);
    }
    float ps[3][8];
    #pragma unroll
    for (int c = 0; c < 3; ++c)
      #pragma unroll
      for (int q = 0; q < 8; ++q) ps[c][q] = 0.f;
    float cnt0 = 0.f, cnt1 = 0.f, cnt2 = 0.f;
    #pragma unroll
    for (int r = 0; r < 4; ++r) {
      float d0 = 0.f, d1 = 0.f, d2 = 0.f;
      #pragma unroll
      for (int q = 0; q < 8; ++q) {
        d0 = fmaf(rx[r][q], c0r[q], d0); d1 = fmaf(rx[r][q], c1r[q], d1); d2 = fmaf(rx[r][q], c2r[q], d2);
      }
      d0 = wsum64(d0); d1 = wsum64(d1); d2 = wsum64(d2);
      float e0 = sqr[r] + sqc0 - 2.f * d0;
      float e1 = sqr[r] + sqc1 - 2.f * d1;
      float e2 = sqr[r] + sqc2 - 2.f * d2;
      int bc = 0; float bd = e0;
      if (e1 < bd) { bd = e1; bc = 1; }
      if (e2 < bd) { bd = e2; bc = 2; }
      float f0 = bc == 0 ? 1.f : 0.f, f1 = bc == 1 ? 1.f : 0.f, f2 = bc == 2 ? 1.f : 0.f;
      #pragma unroll
      for (int q = 0; q < 8; ++q) {
        ps[0][q] = fmaf(f0, rx[r][q], ps[0][q]);
        ps[1][q] = fmaf(f1, rx[r][q], ps[1][q]);
        ps[2][q] = fmaf(f2, rx[r][q], ps[2][q]);
      }
      cnt0 += f0; cnt1 += f1; cnt2 += f2;
    }
    #pragma unroll
    for (int c = 0; c < 3; ++c) {
      *(float4*)&wsum[wid * 1536 + c * 512 + 8 * lane]     = make_float4(ps[c][0], ps[c][1], ps[c][2], ps[c][3]);
      *(float4*)&wsum[wid * 1536 + c * 512 + 8 * lane + 4] = make_float4(ps[c][4], ps[c][5], ps[c][6], ps[c][7]);
    }
    if (lane == 0) { wcnt[wid * 3 + 0] = cnt0; wcnt[wid * 3 + 1] = cnt1; wcnt[wid * 3 + 2] = cnt2; }
    __syncthreads();
    float* pP = psums + (size_t)(it & 1) * (64 * 1536);
    float* pC = pcnts + (it & 1) * 192;
    {
      float s = 0.f;
      #pragma unroll 4
      for (int w = 0; w < 16; ++w) s += wsum[w * 1536 + t];
      pP[b * 1536 + t] = s;
      if (t < 512) {
        float s2 = 0.f;
        #pragma unroll 4
        for (int w = 0; w < 16; ++w) s2 += wsum[w * 1536 + 1024 + t];
        pP[b * 1536 + 1024 + t] = s2;
      }
      if (t < 3) {
        float s3 = 0.f;
        for (int w = 0; w < 16; ++w) s3 += wcnt[w * 3 + t];
        pC[b * 3 + t] = s3;
      }
    }
    grid.sync();
    // redundant center update (every block)
    float sA;
    {
      float s0 = 0.f, s1 = 0.f, s2 = 0.f, s3 = 0.f;
      for (int q = 0; q < 64; q += 4) {
        s0 += pP[(q + 0) * 1536 + t]; s1 += pP[(q + 1) * 1536 + t];
        s2 += pP[(q + 2) * 1536 + t]; s3 += pP[(q + 3) * 1536 + t];
      }
      sA = (s0 + s1) + (s2 + s3);
    }
    float sB = 0.f;
    if (t < 512) {
      float s0 = 0.f, s1 = 0.f, s2 = 0.f, s3 = 0.f;
      int idx = 1024 + t;
      for (int q = 0; q < 64; q += 4) {
        s0 += pP[(q + 0) * 1536 + idx]; s1 += pP[(q + 1) * 1536 + idx];
        s2 += pP[(q + 2) * 1536 + idx]; s3 += pP[(q + 3) * 1536 + idx];
      }
      sB = (s0 + s1) + (s2 + s3);
    }
    if (t < 3) {
      float s = 0.f;
      for (int q = 0; q < 64; ++q) s += pC[q * 3 + t];
      wcnt[t] = s;
    }
    __syncthreads();
    cents[t] = sA / fmaxf(wcnt[t >> 9], 1.f);
    if (t < 512) cents[1024 + t] = sB / fmaxf(wcnt[2], 1.f);
    __syncthreads();
  }

  // ---- d1val with final centers
  {
    float4 a = *(const float4*)&cents[8 * lane], bb = *(const float4*)&cents[8 * lane + 4];
    c0r[0]=a.x;c0r[1]=a.y;c0r[2]=a.z;c0r[3]=a.w;c0r[4]=bb.x;c0r[5]=bb.y;c0r[6]=bb.z;c0r[7]=bb.w;
    a = *(const float4*)&cents[512 + 8 * lane]; bb = *(const float4*)&cents[512 + 8 * lane + 4];
    c1r[0]=a.x;c1r[1]=a.y;c1r[2]=a.z;c1r[3]=a.w;c1r[4]=bb.x;c1r[5]=bb.y;c1r[6]=bb.z;c1r[7]=bb.w;
    a = *(const float4*)&cents[1024 + 8 * lane]; bb = *(const float4*)&cents[1024 + 8 * lane + 4];
    c2r[0]=a.x;c2r[1]=a.y;c2r[2]=a.z;c2r[3]=a.w;c2r[4]=bb.x;c2r[5]=bb.y;c2r[6]=bb.z;c2r[7]=bb.w;
  }
  {
    float s0 = 0.f, s1 = 0.f, s2 = 0.f;
    #pragma unroll
    for (int q = 0; q < 8; ++q) {
      s0 = fmaf(c0r[q], c0r[q], s0); s1 = fmaf(c1r[q], c1r[q], s1); s2 = fmaf(c2r[q], c2r[q], s2);
    }
    sqc0 = wsum64(s0); sqc1 = wsum64(s1); sqc2 = wsum64(s2);
  }
  float dcv = wsum64(dcpart[lane]) / (float)NPTS;
  #pragma unroll
  for (int r = 0; r < 4; ++r) {
    float d0 = 0.f, d1 = 0.f, d2 = 0.f;
    #pragma unroll
    for (int q = 0; q < 8; ++q) {
      d0 = fmaf(rx[r][q], c0r[q], d0); d1 = fmaf(rx[r][q], c1r[q], d1); d2 = fmaf(rx[r][q], c2r[q], d2);
    }
    d0 = wsum64(d0); d1 = wsum64(d1); d2 = wsum64(d2);
    if (lane == 0) {
      int row = rbase + r;
      float q0 = sqrtf(fmaxf(sqr[r] + sqc0 - 2.f * d0, 0.f));
      float q1 = sqrtf(fmaxf(sqr[r] + sqc1 - 2.f * d1, 0.f));
      float q2 = sqrtf(fmaxf(sqr[r] + sqc2 - 2.f * d2, 0.f));
      float nr = q1;
      d1v[row * 3 + 0] = (q0 != 0.f) ? (dcv * nr / (q0 * q0)) : 0.f;
      d1v[row * 3 + 1] = (q1 != 0.f) ? (dcv * nr / (q1 * q1)) : 0.f;
      d1v[row * 3 + 2] = (q2 != 0.f) ? (dcv * nr / (q2 * q2)) : 0.f;
    }
  }

  // ---- block 0 tail: tm reduce, kstar -> bottom 3 output rows
  if (b == 0) {
    if (t < 3) {
      float m = 0.f;
      for (int q = 0; q < 64; ++q) m = fmaxf(m, tmpart[q * 3 + t]);
      tmv[t] = m;
    }
    if (wid == 0) {
      float v = kvp[lane]; int i = kip[lane];
      #pragma unroll
      for (int mm = 1; mm < 64; mm <<= 1) {
        float ov = __shfl_xor(v, mm); int oi = __shfl_xor(i, mm);
        if (ov < v || (ov == v && oi < i)) { v = ov; i = oi; }
      }
      if (lane == 0) mbi[0] = i;
    }
    __syncthreads();
    int kstar = mbi[0];
    if (t < 192) {
      int c = t >> 6, j = t & 63;
      float wv = Wh[(size_t)kstar * FOUT + j];
      out[(size_t)(NPTS + c) * FOUT + j] = wv > 0.f ? wv : expm1f(wv);
    }
  }
}

// ---------------- fused MFMA softmax-numerator @ Wh, K-split x4 ----------------
__global__ __launch_bounds__(256) void k_mainA(const float* __restrict__ t2,
    const __hip_bfloat16* __restrict__ WhbT, const float* __restrict__ d1v,
    const float* __restrict__ tm, float* __restrict__ Vpart, float* __restrict__ Spart) {
  int t = threadIdx.x, lane = t & 63, wid = t >> 6;
  int rb = blockIdx.x & 63, ks = blockIdx.x >> 6;
  int R0 = rb * 64, K0 = ks * 1024;
  __shared__ float t2s[3 * 1024];
  for (int idx = t; idx < 3072; idx += 256) {
    int c = idx >> 10, kl = idx & 1023;
    t2s[idx] = t2[c * NPTS + K0 + kl];
  }
  __syncthreads();
  int r = lane & 15, hi = lane >> 4;
  int row_g = R0 + wid * 16 + r;
  float a0 = d1v[row_g * 3 + 0], a1 = d1v[row_g * 3 + 1], a2 = d1v[row_g * 3 + 2];
  float M = fmaf(fabsf(a2), tm[2], fmaf(fabsf(a1), tm[1], fabsf(a0) * tm[0]));
  f32x4 acc[4];
  #pragma unroll
  for (int fn = 0; fn < 4; ++fn) acc[fn] = (f32x4){0.f, 0.f, 0.f, 0.f};
  float Sp = 0.f;
  const __hip_bfloat16* bwB[4];
  #pragma unroll
  for (int fn = 0; fn < 4; ++fn) bwB[fn] = WhbT + (size_t)(fn * 16 + r) * NPTS + K0 + hi * 8;

  for (int kst = 0; kst < 32; ++kst) {
    int kb = kst * 32 + hi * 8;
    f32x4 c0a = *(const f32x4*)&t2s[kb],        c0b = *(const f32x4*)&t2s[kb + 4];
    f32x4 c1a = *(const f32x4*)&t2s[1024 + kb], c1b = *(const f32x4*)&t2s[1024 + kb + 4];
    f32x4 c2a = *(const f32x4*)&t2s[2048 + kb], c2b = *(const f32x4*)&t2s[2048 + kb + 4];
    float pv[8];
    #pragma unroll
    for (int j = 0; j < 4; ++j) {
      float L  = fmaf(a0, c0a[j], fmaf(a1, c1a[j], fmaf(a2, c2a[j], -M)));
      pv[j] = __expf(L);
      float L2 = fmaf(a0, c0b[j], fmaf(a1, c1b[j], fmaf(a2, c2b[j], -M)));
      pv[4 + j] = __expf(L2);
    }
    Sp += ((pv[0] + pv[1]) + (pv[2] + pv[3])) + ((pv[4] + pv[5]) + (pv[6] + pv[7]));
    union { bf16x8 v; __hip_bfloat162 h2[4]; } pa;
    #pragma unroll
    for (int jj = 0; jj < 4; ++jj) {
      float2 f2; f2.x = pv[2 * jj]; f2.y = pv[2 * jj + 1];
      pa.h2[jj] = __float22bfloat162_rn(f2);
    }
    #pragma unroll
    for (int fn = 0; fn < 4; ++fn) {
      bf16x8 bw = *(const bf16x8*)(bwB[fn] + kst * 32);
      acc[fn] = __builtin_amdgcn_mfma_f32_16x16x32_bf16(pa.v, bw, acc[fn], 0, 0, 0);
    }
  }
  Sp += __shfl_xor(Sp, 16);
  Sp += __shfl_xor(Sp, 32);
  if (hi == 0) Spart[row_g * 4 + ks] = Sp;
  #pragma unroll
  for (int fn = 0; fn < 4; ++fn)
    #pragma unroll
    for (int q = 0; q < 4; ++q)
      Vpart[(size_t)ks * (NPTS * FOUT) + (size_t)(R0 + wid * 16 + hi * 4 + q) * FOUT + fn * 16 + r] = acc[fn][q];
}

// ---------------- combine partials: divide, ELU ----------------
__global__ __launch_bounds__(256) void k_comb(const float* __restrict__ Vpart,
    const float* __restrict__ Spart, const float* __restrict__ d1v,
    const float* __restrict__ tm, float* __restrict__ out) {
  int gid = blockIdx.x * 256 + threadIdx.x;
  int row = gid >> 6;
  float V = (Vpart[gid] + Vpart[NPTS * FOUT + gid])
          + (Vpart[2 * NPTS * FOUT + gid] + Vpart[3 * NPTS * FOUT + gid]);
  float s = (Spart[row * 4 + 0] + Spart[row * 4 + 1]) + (Spart[row * 4 + 2] + Spart[row * 4 + 3]);
  float a0 = d1v[row * 3 + 0], a1 = d1v[row * 3 + 1], a2 = d1v[row * 3 + 2];
  float M = fmaf(fabsf(a2), tm[2], fmaf(fabsf(a1), tm[1], fabsf(a0) * tm[0]));
  s += 3.f * __expf(-M);
  float o = V / s;
  out[gid] = o > 0.f ? o : expm1f(o);
}

extern "C" void kernel_launch(void* const* d_in, const int* in_sizes, int n_in,
                              void* d_out, int out_size, void* d_ws, size_t ws_size,
                              hipStream_t stream) {
  const float* h  = (const float*)d_in[0];
  const float* W  = (const float*)d_in[2];
  const float* t2 = (const float*)d_in[5];
  float* out = (float*)d_out;

  char* ws = (char*)d_ws;
  __hip_bfloat16* xb = (__hip_bfloat16*)ws;
  float* F = (float*)(ws + (size_t)NPTS * FIN * 2);
  float* sq   = F + 0;                   // 4096
  int*   m1   = (int*)(F + 4096);        // 4096
  float* d1v  = F + 16384;               // 12288
  float* Wh   = F + 32768;               // 262144
  float* tmv  = F + 298248;              // 3
  float* Spart = F + 691712;             // 16384
  float* Vpart = F + 708096;             // 1048576
  __hip_bfloat16* WhbT = (__hip_bfloat16*)(F + 1756672); // 262144 bf16 = 131072 floats
  float* G = F + 1900544;                // coop scratch (~198K floats)

  k_prep<<<NPTS / 4, 256, 0, stream>>>(h, W, xb, sq, m1, Wh);
  k_tr<<<16, 256, 0, stream>>>(Wh, WhbT);
  k_gram2<<<528, 256, 0, stream>>>(xb, sq, m1);

  {
    const float* hh = h; const float* sqp = sq; const int* m1p = m1;
    const float* t2p = t2; const float* Whp = Wh;
    float* Gp = G; float* d1vp = d1v; float* tmvp = tmv; float* outp = out;
    void* kargs[] = { (void*)&hh, (void*)&sqp, (void*)&m1p, (void*)&t2p, (void*)&Whp,
                      (void*)&Gp, (void*)&d1vp, (void*)&tmvp, (void*)&outp };
    unsigned smem_bytes = (16 * 1536 + 1536 + 48 + 16 + 16) * 4; // 104768
    hipLaunchCooperativeKernel((void*)k_km, dim3(64), dim3(1024), kargs, smem_bytes, stream);
  }

  k_mainA<<<256, 256, 0, stream>>>(t2, WhbT, d1v, tmv, Vpart, Spart);
  k_comb<<<1024, 256, 0, stream>>>(Vpart, Spart, d1v, tmv, out);
}

// Round 5
// 254.660 us; speedup vs baseline: 1.4140x; 1.4140x over previous
//
#include <hip/hip_runtime.h>
#include <hip/hip_bf16.h>
#include <math.h>

#define NPTS 4096
#define FIN 512
#define FOUT 64

typedef __attribute__((ext_vector_type(8))) short bf16x8;
typedef __attribute__((ext_vector_type(4))) float f32x4;

static __device__ __forceinline__ unsigned short bfbits(float x) {
  __hip_bfloat16 b = __float2bfloat16(x);
  return *reinterpret_cast<unsigned short*>(&b);
}

static __device__ __forceinline__ float wsum64(float v) {
  #pragma unroll
  for (int mm = 1; mm < 64; mm <<= 1) v += __shfl_xor(v, mm);
  return v;
}

// ---------------- prep: bf16 copy of h, row norms, init m1, Wh = h@W ----------------
__global__ __launch_bounds__(256) void k_prep(const float* __restrict__ h,
    const float* __restrict__ W, __hip_bfloat16* __restrict__ xb,
    float* __restrict__ sq, int* __restrict__ m1, float* __restrict__ Wh) {
  __shared__ float hs[4][512];
  int t = threadIdx.x, lane = t & 63, wid = t >> 6;
  int row = blockIdx.x * 4 + wid;
  const float4* hr = (const float4*)(h + (size_t)row * FIN);
  float4 a = hr[lane], b = hr[64 + lane];
  ushort4 pa = { bfbits(a.x), bfbits(a.y), bfbits(a.z), bfbits(a.w) };
  ushort4 pb = { bfbits(b.x), bfbits(b.y), bfbits(b.z), bfbits(b.w) };
  *(ushort4*)(xb + (size_t)row * FIN + 4 * lane) = pa;
  *(ushort4*)(xb + (size_t)row * FIN + 256 + 4 * lane) = pb;
  float s = a.x*a.x + a.y*a.y + a.z*a.z + a.w*a.w
          + b.x*b.x + b.y*b.y + b.z*b.z + b.w*b.w;
  s = wsum64(s);
  if (lane == 0) { sq[row] = s; m1[row] = 0x7F800000; }
  *(float4*)&hs[wid][4 * lane] = a;
  *(float4*)&hs[wid][256 + 4 * lane] = b;
  __syncthreads();
  float a0 = 0.f, a1 = 0.f, a2 = 0.f, a3 = 0.f;
  #pragma unroll 2
  for (int k = 0; k < 512; k += 4) {
    a0 = fmaf(hs[wid][k + 0], W[(k + 0) * FOUT + lane], a0);
    a1 = fmaf(hs[wid][k + 1], W[(k + 1) * FOUT + lane], a1);
    a2 = fmaf(hs[wid][k + 2], W[(k + 2) * FOUT + lane], a2);
    a3 = fmaf(hs[wid][k + 3], W[(k + 3) * FOUT + lane], a3);
  }
  Wh[(size_t)row * FOUT + lane] = (a0 + a1) + (a2 + a3);
}

// ---------------- transpose Wh -> WhbT (bf16, [64][4096]) ----------------
__global__ __launch_bounds__(256) void k_tr(const float* __restrict__ Wh,
    __hip_bfloat16* __restrict__ WhbT) {
  __shared__ __hip_bfloat16 tT[64][264];
  int t = threadIdx.x;
  int kbase = blockIdx.x * 256;
  for (int rep = 0; rep < 64; ++rep) {
    int idx = t + rep * 256;
    int k = idx >> 6, n = idx & 63;
    tT[n][k] = __float2bfloat16(Wh[(size_t)(kbase + k) * FOUT + n]);
  }
  __syncthreads();
  int n = t >> 2, kq = t & 3;
  #pragma unroll
  for (int rep = 0; rep < 8; ++rep) {
    int kk = kq * 64 + rep * 8;
    bf16x8 v = *(const bf16x8*)&tT[n][kk];
    *(bf16x8*)(WhbT + (size_t)n * NPTS + kbase + kk) = v;
  }
}

// ---------------- Gram + per-row NN-min: LDS-staged MFMA, triangular grid ----------------
__global__ __launch_bounds__(256) void k_gram2(const __hip_bfloat16* __restrict__ xb,
    const float* __restrict__ sq, int* __restrict__ m1) {
  int b = blockIdx.x, I = 0;
  while (b >= 32 - I) { b -= 32 - I; ++I; }
  int J = I + b;
  int tid = threadIdx.x, lane = tid & 63, wid = tid >> 6;

  __shared__ __align__(16) __hip_bfloat16 As[128 * 64];
  __shared__ __align__(16) __hip_bfloat16 Bs[128 * 64];

  int R0 = I * 128, C0 = J * 128;
  int rowBase = (wid >> 1) * 64;
  int colBase = (wid & 1) * 64;
  int lrow = lane & 15, hi = lane >> 4, rsub = hi * 4;

  f32x4 acc[4][4];
  #pragma unroll
  for (int p = 0; p < 4; ++p)
    #pragma unroll
    for (int q = 0; q < 4; ++q)
      acc[p][q] = (f32x4){0.f, 0.f, 0.f, 0.f};

  int srow = lane >> 3;
  int scol = ((lane & 7) ^ srow) * 8;
  const __hip_bfloat16* gA = xb + (size_t)(R0 + wid * 32 + srow) * FIN + scol;
  const __hip_bfloat16* gB = xb + (size_t)(C0 + wid * 32 + srow) * FIN + scol;
  char* lA = (char*)As + wid * 4096;
  char* lB = (char*)Bs + wid * 4096;
  int rdswz = (lrow & 7) << 4;

  for (int kt = 0; kt < 8; ++kt) {
    int K0 = kt * 64;
    #pragma unroll
    for (int j = 0; j < 4; ++j) {
      __builtin_amdgcn_global_load_lds(
          (const __attribute__((address_space(1))) unsigned int*)(gA + (size_t)(8 * j) * FIN + K0),
          (__attribute__((address_space(3))) unsigned int*)(lA + j * 1024), 16, 0, 0);
      __builtin_amdgcn_global_load_lds(
          (const __attribute__((address_space(1))) unsigned int*)(gB + (size_t)(8 * j) * FIN + K0),
          (__attribute__((address_space(3))) unsigned int*)(lB + j * 1024), 16, 0, 0);
    }
    __syncthreads();
    #pragma unroll
    for (int s = 0; s < 2; ++s) {
      int k0b = s * 64;
      bf16x8 av[4], bw[4];
      #pragma unroll
      for (int f = 0; f < 4; ++f) {
        int arow = rowBase + f * 16 + lrow;
        av[f] = *(const bf16x8*)((const char*)As + arow * 128 + ((k0b + hi * 16) ^ rdswz));
        int brow = colBase + f * 16 + lrow;
        bw[f] = *(const bf16x8*)((const char*)Bs + brow * 128 + ((k0b + hi * 16) ^ rdswz));
      }
      #pragma unroll
      for (int fi = 0; fi < 4; ++fi)
        #pragma unroll
        for (int fj = 0; fj < 4; ++fj)
          acc[fi][fj] = __builtin_amdgcn_mfma_f32_16x16x32_bf16(av[fi], bw[fj], acc[fi][fj], 0, 0, 0);
    }
    __syncthreads();
  }

  int rowBaseG = R0 + rowBase, colBaseG = C0 + colBase;
  float sqr[16], sqc4[4];
  #pragma unroll
  for (int fi = 0; fi < 4; ++fi)
    #pragma unroll
    for (int rg = 0; rg < 4; ++rg)
      sqr[fi * 4 + rg] = sq[rowBaseG + fi * 16 + rsub + rg];
  #pragma unroll
  for (int fj = 0; fj < 4; ++fj) sqc4[fj] = sq[colBaseG + fj * 16 + lrow];

  float rmin[16], cmin[4];
  #pragma unroll
  for (int q = 0; q < 16; ++q) rmin[q] = INFINITY;
  #pragma unroll
  for (int q = 0; q < 4; ++q) cmin[q] = INFINITY;

  #pragma unroll
  for (int fi = 0; fi < 4; ++fi)
    #pragma unroll
    for (int fj = 0; fj < 4; ++fj)
      #pragma unroll
      for (int rg = 0; rg < 4; ++rg) {
        int r = rowBaseG + fi * 16 + rsub + rg;
        int c = colBaseG + fj * 16 + lrow;
        float d2 = sqr[fi * 4 + rg] + sqc4[fj] - 2.f * acc[fi][fj][rg];
        if (r == c) d2 = INFINITY;
        rmin[fi * 4 + rg] = fminf(rmin[fi * 4 + rg], d2);
        cmin[fj] = fminf(cmin[fj], d2);
      }

  #pragma unroll
  for (int mm = 1; mm < 16; mm <<= 1) {
    #pragma unroll
    for (int q = 0; q < 16; ++q) rmin[q] = fminf(rmin[q], __shfl_xor(rmin[q], mm));
  }
  if ((lane & 15) == 0) {
    #pragma unroll
    for (int q = 0; q < 16; ++q) {
      int r = rowBaseG + (q >> 2) * 16 + rsub + (q & 3);
      atomicMin(&m1[r], __float_as_int(rmin[q]));
    }
  }
  if (I != J) {
    #pragma unroll
    for (int mm = 16; mm < 64; mm <<= 1) {
      #pragma unroll
      for (int q = 0; q < 4; ++q) cmin[q] = fminf(cmin[q], __shfl_xor(cmin[q], mm));
    }
    if ((lane >> 4) == 0) {
      #pragma unroll
      for (int q = 0; q < 4; ++q)
        atomicMin(&m1[colBaseG + q * 16 + lane], __float_as_int(cmin[q]));
    }
  }
}

// ---------------- farthest-point pass A + side partials (dc/tm/kstar) ----------------
__global__ __launch_bounds__(512) void k_fp0(const float* __restrict__ h,
    const int* __restrict__ m1, const float* __restrict__ t2,
    float* __restrict__ dkm, float* __restrict__ bvA, int* __restrict__ biA,
    float* __restrict__ dcpart, float* __restrict__ tmpart,
    float* __restrict__ kvp, int* __restrict__ kip) {
  int t = threadIdx.x, lane = t & 63, wid = t >> 6, b = blockIdx.x;
  __shared__ float rv[8]; __shared__ int ri[8];
  float cr[8];
  {
    const float4* cp = (const float4*)h;
    float4 u0 = cp[2 * lane], u1 = cp[2 * lane + 1];
    cr[0]=u0.x;cr[1]=u0.y;cr[2]=u0.z;cr[3]=u0.w;cr[4]=u1.x;cr[5]=u1.y;cr[6]=u1.z;cr[7]=u1.w;
  }
  int rbase = b * 64 + wid * 8;
  float bv = -1.f; int bi = 0;
  for (int r = 0; r < 8; ++r) {
    int row = rbase + r;
    const float4* xr = (const float4*)(h + (size_t)row * FIN);
    float4 xa = xr[2 * lane], xb4 = xr[2 * lane + 1];
    float x[8] = {xa.x, xa.y, xa.z, xa.w, xb4.x, xb4.y, xb4.z, xb4.w};
    float d = 0.f;
    #pragma unroll
    for (int q = 0; q < 8; ++q) { float df = x[q] - cr[q]; d = fmaf(df, df, d); }
    d = wsum64(d);
    if (lane == 0) dkm[row] = d;
    if (d > bv) { bv = d; bi = row; }
  }
  if (lane == 0) { rv[wid] = bv; ri[wid] = bi; }
  // side partials
  if (wid == 1) {
    #pragma unroll
    for (int c = 0; c < 3; ++c) {
      float m = fabsf(t2[c * NPTS + b * 64 + lane]);
      #pragma unroll
      for (int mm = 1; mm < 64; mm <<= 1) m = fmaxf(m, __shfl_xor(m, mm));
      if (lane == 0) tmpart[b * 3 + c] = m;
    }
  } else if (wid == 2) {
    int k = b * 64 + lane;
    float v = t2[k] + t2[NPTS + k] + t2[2 * NPTS + k];
    int ki = k;
    #pragma unroll
    for (int mm = 1; mm < 64; mm <<= 1) {
      float ov = __shfl_xor(v, mm); int oi = __shfl_xor(ki, mm);
      if (ov < v || (ov == v && oi < ki)) { v = ov; ki = oi; }
    }
    if (lane == 0) { kvp[b] = v; kip[b] = ki; }
  } else if (wid == 3) {
    float v = sqrtf(fmaxf(__int_as_float(m1[b * 64 + lane]), 0.f));
    v = wsum64(v);
    if (lane == 0) dcpart[b] = v;
  }
  __syncthreads();
  if (t == 0) {
    float vv = rv[0]; int ii = ri[0];
    for (int w = 1; w < 8; ++w)
      if (rv[w] > vv || (rv[w] == vv && ri[w] < ii)) { vv = rv[w]; ii = ri[w]; }
    bvA[b] = vv; biA[b] = ii;
  }
}

// ---------------- farthest-point pass B ----------------
__global__ __launch_bounds__(512) void k_fp1(const float* __restrict__ h,
    float* __restrict__ dkm, const float* __restrict__ bvA, const int* __restrict__ biA,
    float* __restrict__ bvB, int* __restrict__ biB, int* __restrict__ b1s) {
  int t = threadIdx.x, lane = t & 63, wid = t >> 6, b = blockIdx.x;
  __shared__ float rv[8]; __shared__ int ri[8]; __shared__ int sb1;
  if (wid == 0) {
    float v = bvA[lane]; int i = biA[lane];
    #pragma unroll
    for (int mm = 1; mm < 64; mm <<= 1) {
      float ov = __shfl_xor(v, mm); int oi = __shfl_xor(i, mm);
      if (ov > v || (ov == v && oi < i)) { v = ov; i = oi; }
    }
    if (lane == 0) sb1 = i;
  }
  __syncthreads();
  int b1 = sb1;
  if (b == 0 && t == 0) b1s[0] = b1;
  float cr[8];
  {
    const float4* cp = (const float4*)(h + (size_t)b1 * FIN);
    float4 u0 = cp[2 * lane], u1 = cp[2 * lane + 1];
    cr[0]=u0.x;cr[1]=u0.y;cr[2]=u0.z;cr[3]=u0.w;cr[4]=u1.x;cr[5]=u1.y;cr[6]=u1.z;cr[7]=u1.w;
  }
  int rbase = b * 64 + wid * 8;
  float bv = -1.f; int bi = 0;
  for (int r = 0; r < 8; ++r) {
    int row = rbase + r;
    const float4* xr = (const float4*)(h + (size_t)row * FIN);
    float4 xa = xr[2 * lane], xb4 = xr[2 * lane + 1];
    float x[8] = {xa.x, xa.y, xa.z, xa.w, xb4.x, xb4.y, xb4.z, xb4.w};
    float d = 0.f;
    #pragma unroll
    for (int q = 0; q < 8; ++q) { float df = x[q] - cr[q]; d = fmaf(df, df, d); }
    d = wsum64(d);
    d = fminf(d, dkm[row]);
    if (lane == 0) dkm[row] = d;
    if (d > bv) { bv = d; bi = row; }
  }
  if (lane == 0) { rv[wid] = bv; ri[wid] = bi; }
  __syncthreads();
  if (t == 0) {
    float vv = rv[0]; int ii = ri[0];
    for (int w = 1; w < 8; ++w)
      if (rv[w] > vv || (rv[w] == vv && ri[w] < ii)) { vv = rv[w]; ii = ri[w]; }
    bvB[b] = vv; biB[b] = ii;
  }
}

// ---------------- shared Lloyd assign helper (64 blocks x 512, 8 rows/wave) ----------------
__device__ __forceinline__ void lloyd_assign(const float* __restrict__ h,
    const float* __restrict__ sq, const float* cents, float* wsum, float* wcnt,
    float* __restrict__ psOut, float* __restrict__ pcOut) {
  int t = threadIdx.x, lane = t & 63, wid = t >> 6, b = blockIdx.x;
  float c0r[8], c1r[8], c2r[8];
  {
    float4 u;
    u = *(const float4*)&cents[8 * lane];          c0r[0]=u.x;c0r[1]=u.y;c0r[2]=u.z;c0r[3]=u.w;
    u = *(const float4*)&cents[8 * lane + 4];      c0r[4]=u.x;c0r[5]=u.y;c0r[6]=u.z;c0r[7]=u.w;
    u = *(const float4*)&cents[512 + 8 * lane];    c1r[0]=u.x;c1r[1]=u.y;c1r[2]=u.z;c1r[3]=u.w;
    u = *(const float4*)&cents[512 + 8 * lane + 4];c1r[4]=u.x;c1r[5]=u.y;c1r[6]=u.z;c1r[7]=u.w;
    u = *(const float4*)&cents[1024 + 8 * lane];   c2r[0]=u.x;c2r[1]=u.y;c2r[2]=u.z;c2r[3]=u.w;
    u = *(const float4*)&cents[1024 + 8*lane + 4]; c2r[4]=u.x;c2r[5]=u.y;c2r[6]=u.z;c2r[7]=u.w;
  }
  float s0 = 0.f, s1 = 0.f, s2 = 0.f;
  #pragma unroll
  for (int q = 0; q < 8; ++q) {
    s0 = fmaf(c0r[q], c0r[q], s0); s1 = fmaf(c1r[q], c1r[q], s1); s2 = fmaf(c2r[q], c2r[q], s2);
  }
  float sqc0 = wsum64(s0), sqc1 = wsum64(s1), sqc2 = wsum64(s2);

  float ps[3][8];
  #pragma unroll
  for (int c = 0; c < 3; ++c)
    #pragma unroll
    for (int q = 0; q < 8; ++q) ps[c][q] = 0.f;
  float cnt0 = 0.f, cnt1 = 0.f, cnt2 = 0.f;
  int rbase = b * 64 + wid * 8;
  for (int r = 0; r < 8; ++r) {
    int row = rbase + r;
    const float4* xr = (const float4*)(h + (size_t)row * FIN);
    float4 xa = xr[2 * lane], xb4 = xr[2 * lane + 1];
    float x[8] = {xa.x, xa.y, xa.z, xa.w, xb4.x, xb4.y, xb4.z, xb4.w};
    float d0 = 0.f, d1 = 0.f, d2 = 0.f;
    #pragma unroll
    for (int q = 0; q < 8; ++q) {
      d0 = fmaf(x[q], c0r[q], d0); d1 = fmaf(x[q], c1r[q], d1); d2 = fmaf(x[q], c2r[q], d2);
    }
    d0 = wsum64(d0); d1 = wsum64(d1); d2 = wsum64(d2);
    float sr = sq[row];
    float e0 = sr + sqc0 - 2.f * d0;
    float e1 = sr + sqc1 - 2.f * d1;
    float e2 = sr + sqc2 - 2.f * d2;
    int bc = 0; float bd = e0;
    if (e1 < bd) { bd = e1; bc = 1; }
    if (e2 < bd) { bd = e2; bc = 2; }
    float f0 = bc == 0 ? 1.f : 0.f, f1 = bc == 1 ? 1.f : 0.f, f2 = bc == 2 ? 1.f : 0.f;
    #pragma unroll
    for (int q = 0; q < 8; ++q) {
      ps[0][q] = fmaf(f0, x[q], ps[0][q]);
      ps[1][q] = fmaf(f1, x[q], ps[1][q]);
      ps[2][q] = fmaf(f2, x[q], ps[2][q]);
    }
    cnt0 += f0; cnt1 += f1; cnt2 += f2;
  }
  #pragma unroll
  for (int c = 0; c < 3; ++c) {
    *(float4*)&wsum[wid * 1536 + c * 512 + 8 * lane]     = make_float4(ps[c][0], ps[c][1], ps[c][2], ps[c][3]);
    *(float4*)&wsum[wid * 1536 + c * 512 + 8 * lane + 4] = make_float4(ps[c][4], ps[c][5], ps[c][6], ps[c][7]);
  }
  if (lane == 0) { wcnt[wid * 3 + 0] = cnt0; wcnt[wid * 3 + 1] = cnt1; wcnt[wid * 3 + 2] = cnt2; }
  __syncthreads();
  for (int idx = t; idx < 1536; idx += 512) {
    float s = ((wsum[0 * 1536 + idx] + wsum[1 * 1536 + idx]) + (wsum[2 * 1536 + idx] + wsum[3 * 1536 + idx]))
            + ((wsum[4 * 1536 + idx] + wsum[5 * 1536 + idx]) + (wsum[6 * 1536 + idx] + wsum[7 * 1536 + idx]));
    psOut[(size_t)b * 1536 + idx] = s;
  }
  if (t < 3) {
    float s = 0.f;
    for (int w = 0; w < 8; ++w) s += wcnt[w * 3 + t];
    pcOut[b * 3 + t] = s;
  }
}

// ---------------- Lloyd iter 0: init centers from (0, b1, b2), assign ----------------
__global__ __launch_bounds__(512) void k_lloyd0(const float* __restrict__ h,
    const float* __restrict__ sq, const float* __restrict__ bvB, const int* __restrict__ biB,
    const int* __restrict__ b1s, float* __restrict__ psOut, float* __restrict__ pcOut) {
  __shared__ float cents[1536];
  __shared__ float wsum[8 * 1536];
  __shared__ float wcnt[24];
  __shared__ int sb2;
  int t = threadIdx.x, lane = t & 63, wid = t >> 6;
  if (wid == 0) {
    float v = bvB[lane]; int i = biB[lane];
    #pragma unroll
    for (int mm = 1; mm < 64; mm <<= 1) {
      float ov = __shfl_xor(v, mm); int oi = __shfl_xor(i, mm);
      if (ov > v || (ov == v && oi < i)) { v = ov; i = oi; }
    }
    if (lane == 0) sb2 = i;
  }
  __syncthreads();
  int b1 = b1s[0], b2 = sb2;
  cents[t]        = h[t];
  cents[512 + t]  = h[(size_t)b1 * FIN + t];
  cents[1024 + t] = h[(size_t)b2 * FIN + t];
  __syncthreads();
  lloyd_assign(h, sq, cents, wsum, wcnt, psOut, pcOut);
}

// ---------------- Lloyd iter k: reduce psums -> centers, assign ----------------
__global__ __launch_bounds__(512) void k_lloyd(const float* __restrict__ h,
    const float* __restrict__ sq, const float* __restrict__ psIn, const float* __restrict__ pcIn,
    float* __restrict__ psOut, float* __restrict__ pcOut) {
  __shared__ float cents[1536];
  __shared__ float wsum[8 * 1536];
  __shared__ float wcnt[24];
  __shared__ float cntS[3];
  int t = threadIdx.x;
  if (t < 3) {
    float s = 0.f;
    for (int q = 0; q < 64; ++q) s += pcIn[q * 3 + t];
    cntS[t] = s;
  }
  float a[3][8];
  #pragma unroll
  for (int c = 0; c < 3; ++c)
    #pragma unroll
    for (int j = 0; j < 8; ++j) a[c][j] = 0.f;
  #pragma unroll
  for (int m = 0; m < 8; ++m)
    #pragma unroll
    for (int c = 0; c < 3; ++c)
      #pragma unroll
      for (int j = 0; j < 8; ++j)
        a[c][j] += psIn[(size_t)(m * 8 + j) * 1536 + c * 512 + t];
  __syncthreads();
  #pragma unroll
  for (int c = 0; c < 3; ++c) {
    float s = ((a[c][0] + a[c][1]) + (a[c][2] + a[c][3])) + ((a[c][4] + a[c][5]) + (a[c][6] + a[c][7]));
    cents[c * 512 + t] = s / fmaxf(cntS[c], 1.f);
  }
  __syncthreads();
  lloyd_assign(h, sq, cents, wsum, wcnt, psOut, pcOut);
}

// ---------------- finalize: centers, dc, d1val, tm/kstar tail ----------------
__global__ __launch_bounds__(512) void k_fin(const float* __restrict__ h,
    const float* __restrict__ sq, const float* __restrict__ psIn, const float* __restrict__ pcIn,
    const float* __restrict__ dcpart, const float* __restrict__ tmpart,
    const float* __restrict__ kvp, const int* __restrict__ kip,
    const float* __restrict__ Wh, float* __restrict__ d1v,
    float* __restrict__ tmv, float* __restrict__ out) {
  __shared__ float cents[1536];
  __shared__ float cntS[3];
  __shared__ int skstar;
  int t = threadIdx.x, lane = t & 63, wid = t >> 6, b = blockIdx.x;
  if (t < 3) {
    float s = 0.f;
    for (int q = 0; q < 64; ++q) s += pcIn[q * 3 + t];
    cntS[t] = s;
  }
  float a[3][8];
  #pragma unroll
  for (int c = 0; c < 3; ++c)
    #pragma unroll
    for (int j = 0; j < 8; ++j) a[c][j] = 0.f;
  #pragma unroll
  for (int m = 0; m < 8; ++m)
    #pragma unroll
    for (int c = 0; c < 3; ++c)
      #pragma unroll
      for (int j = 0; j < 8; ++j)
        a[c][j] += psIn[(size_t)(m * 8 + j) * 1536 + c * 512 + t];
  __syncthreads();
  #pragma unroll
  for (int c = 0; c < 3; ++c) {
    float s = ((a[c][0] + a[c][1]) + (a[c][2] + a[c][3])) + ((a[c][4] + a[c][5]) + (a[c][6] + a[c][7]));
    cents[c * 512 + t] = s / fmaxf(cntS[c], 1.f);
  }
  __syncthreads();
  float c0r[8], c1r[8], c2r[8];
  {
    float4 u;
    u = *(const float4*)&cents[8 * lane];          c0r[0]=u.x;c0r[1]=u.y;c0r[2]=u.z;c0r[3]=u.w;
    u = *(const float4*)&cents[8 * lane + 4];      c0r[4]=u.x;c0r[5]=u.y;c0r[6]=u.z;c0r[7]=u.w;
    u = *(const float4*)&cents[512 + 8 * lane];    c1r[0]=u.x;c1r[1]=u.y;c1r[2]=u.z;c1r[3]=u.w;
    u = *(const float4*)&cents[512 + 8 * lane + 4];c1r[4]=u.x;c1r[5]=u.y;c1r[6]=u.z;c1r[7]=u.w;
    u = *(const float4*)&cents[1024 + 8 * lane];   c2r[0]=u.x;c2r[1]=u.y;c2r[2]=u.z;c2r[3]=u.w;
    u = *(const float4*)&cents[1024 + 8*lane + 4]; c2r[4]=u.x;c2r[5]=u.y;c2r[6]=u.z;c2r[7]=u.w;
  }
  float s0 = 0.f, s1 = 0.f, s2 = 0.f;
  #pragma unroll
  for (int q = 0; q < 8; ++q) {
    s0 = fmaf(c0r[q], c0r[q], s0); s1 = fmaf(c1r[q], c1r[q], s1); s2 = fmaf(c2r[q], c2r[q], s2);
  }
  float sqc0 = wsum64(s0), sqc1 = wsum64(s1), sqc2 = wsum64(s2);
  float dcv = wsum64(dcpart[lane]) / (float)NPTS;
  int rbase = b * 64 + wid * 8;
  for (int r = 0; r < 8; ++r) {
    int row = rbase + r;
    const float4* xr = (const float4*)(h + (size_t)row * FIN);
    float4 xa = xr[2 * lane], xb4 = xr[2 * lane + 1];
    float x[8] = {xa.x, xa.y, xa.z, xa.w, xb4.x, xb4.y, xb4.z, xb4.w};
    float d0 = 0.f, d1 = 0.f, d2 = 0.f;
    #pragma unroll
    for (int q = 0; q < 8; ++q) {
      d0 = fmaf(x[q], c0r[q], d0); d1 = fmaf(x[q], c1r[q], d1); d2 = fmaf(x[q], c2r[q], d2);
    }
    d0 = wsum64(d0); d1 = wsum64(d1); d2 = wsum64(d2);
    if (lane == 0) {
      float sr = sq[row];
      float q0 = sqrtf(fmaxf(sr + sqc0 - 2.f * d0, 0.f));
      float q1 = sqrtf(fmaxf(sr + sqc1 - 2.f * d1, 0.f));
      float q2 = sqrtf(fmaxf(sr + sqc2 - 2.f * d2, 0.f));
      float nr = q1;
      d1v[row * 3 + 0] = (q0 != 0.f) ? (dcv * nr / (q0 * q0)) : 0.f;
      d1v[row * 3 + 1] = (q1 != 0.f) ? (dcv * nr / (q1 * q1)) : 0.f;
      d1v[row * 3 + 2] = (q2 != 0.f) ? (dcv * nr / (q2 * q2)) : 0.f;
    }
  }
  if (b == 0) {
    if (t < 3) {
      float m = 0.f;
      for (int q = 0; q < 64; ++q) m = fmaxf(m, tmpart[q * 3 + t]);
      tmv[t] = m;
    }
    if (wid == 0) {
      float v = kvp[lane]; int i = kip[lane];
      #pragma unroll
      for (int mm = 1; mm < 64; mm <<= 1) {
        float ov = __shfl_xor(v, mm); int oi = __shfl_xor(i, mm);
        if (ov < v || (ov == v && oi < i)) { v = ov; i = oi; }
      }
      if (lane == 0) skstar = i;
    }
    __syncthreads();
    int kstar = skstar;
    if (t < 192) {
      int c = t >> 6, j = t & 63;
      float wv = Wh[(size_t)kstar * FOUT + j];
      out[(size_t)(NPTS + c) * FOUT + j] = wv > 0.f ? wv : expm1f(wv);
    }
  }
}

// ---------------- fused MFMA softmax-numerator @ Wh, K-split x4 ----------------
__global__ __launch_bounds__(256) void k_mainA(const float* __restrict__ t2,
    const __hip_bfloat16* __restrict__ WhbT, const float* __restrict__ d1v,
    const float* __restrict__ tm, float* __restrict__ Vpart, float* __restrict__ Spart) {
  int t = threadIdx.x, lane = t & 63, wid = t >> 6;
  int rb = blockIdx.x & 63, ks = blockIdx.x >> 6;
  int R0 = rb * 64, K0 = ks * 1024;
  __shared__ float t2s[3 * 1024];
  for (int idx = t; idx < 3072; idx += 256) {
    int c = idx >> 10, kl = idx & 1023;
    t2s[idx] = t2[c * NPTS + K0 + kl];
  }
  __syncthreads();
  int r = lane & 15, hi = lane >> 4;
  int row_g = R0 + wid * 16 + r;
  float a0 = d1v[row_g * 3 + 0], a1 = d1v[row_g * 3 + 1], a2 = d1v[row_g * 3 + 2];
  float M = fmaf(fabsf(a2), tm[2], fmaf(fabsf(a1), tm[1], fabsf(a0) * tm[0]));
  f32x4 acc[4];
  #pragma unroll
  for (int fn = 0; fn < 4; ++fn) acc[fn] = (f32x4){0.f, 0.f, 0.f, 0.f};
  float Sp = 0.f;
  const __hip_bfloat16* bwB[4];
  #pragma unroll
  for (int fn = 0; fn < 4; ++fn) bwB[fn] = WhbT + (size_t)(fn * 16 + r) * NPTS + K0 + hi * 8;

  for (int kst = 0; kst < 32; ++kst) {
    int kb = kst * 32 + hi * 8;
    f32x4 c0a = *(const f32x4*)&t2s[kb],        c0b = *(const f32x4*)&t2s[kb + 4];
    f32x4 c1a = *(const f32x4*)&t2s[1024 + kb], c1b = *(const f32x4*)&t2s[1024 + kb + 4];
    f32x4 c2a = *(const f32x4*)&t2s[2048 + kb], c2b = *(const f32x4*)&t2s[2048 + kb + 4];
    float pv[8];
    #pragma unroll
    for (int j = 0; j < 4; ++j) {
      float L  = fmaf(a0, c0a[j], fmaf(a1, c1a[j], fmaf(a2, c2a[j], -M)));
      pv[j] = __expf(L);
      float L2 = fmaf(a0, c0b[j], fmaf(a1, c1b[j], fmaf(a2, c2b[j], -M)));
      pv[4 + j] = __expf(L2);
    }
    Sp += ((pv[0] + pv[1]) + (pv[2] + pv[3])) + ((pv[4] + pv[5]) + (pv[6] + pv[7]));
    union { bf16x8 v; __hip_bfloat162 h2[4]; } pa;
    #pragma unroll
    for (int jj = 0; jj < 4; ++jj) {
      float2 f2; f2.x = pv[2 * jj]; f2.y = pv[2 * jj + 1];
      pa.h2[jj] = __float22bfloat162_rn(f2);
    }
    #pragma unroll
    for (int fn = 0; fn < 4; ++fn) {
      bf16x8 bw = *(const bf16x8*)(bwB[fn] + kst * 32);
      acc[fn] = __builtin_amdgcn_mfma_f32_16x16x32_bf16(pa.v, bw, acc[fn], 0, 0, 0);
    }
  }
  Sp += __shfl_xor(Sp, 16);
  Sp += __shfl_xor(Sp, 32);
  if (hi == 0) Spart[row_g * 4 + ks] = Sp;
  #pragma unroll
  for (int fn = 0; fn < 4; ++fn)
    #pragma unroll
    for (int q = 0; q < 4; ++q)
      Vpart[(size_t)ks * (NPTS * FOUT) + (size_t)(R0 + wid * 16 + hi * 4 + q) * FOUT + fn * 16 + r] = acc[fn][q];
}

// ---------------- combine partials: divide, ELU ----------------
__global__ __launch_bounds__(256) void k_comb(const float* __restrict__ Vpart,
    const float* __restrict__ Spart, const float* __restrict__ d1v,
    const float* __restrict__ tm, float* __restrict__ out) {
  int gid = blockIdx.x * 256 + threadIdx.x;
  int row = gid >> 6;
  float V = (Vpart[gid] + Vpart[NPTS * FOUT + gid])
          + (Vpart[2 * NPTS * FOUT + gid] + Vpart[3 * NPTS * FOUT + gid]);
  float s = (Spart[row * 4 + 0] + Spart[row * 4 + 1]) + (Spart[row * 4 + 2] + Spart[row * 4 + 3]);
  float a0 = d1v[row * 3 + 0], a1 = d1v[row * 3 + 1], a2 = d1v[row * 3 + 2];
  float M = fmaf(fabsf(a2), tm[2], fmaf(fabsf(a1), tm[1], fabsf(a0) * tm[0]));
  s += 3.f * __expf(-M);
  float o = V / s;
  out[gid] = o > 0.f ? o : expm1f(o);
}

extern "C" void kernel_launch(void* const* d_in, const int* in_sizes, int n_in,
                              void* d_out, int out_size, void* d_ws, size_t ws_size,
                              hipStream_t stream) {
  const float* h  = (const float*)d_in[0];
  const float* W  = (const float*)d_in[2];
  const float* t2 = (const float*)d_in[5];
  float* out = (float*)d_out;

  char* ws = (char*)d_ws;
  __hip_bfloat16* xb = (__hip_bfloat16*)ws;
  float* F = (float*)(ws + (size_t)NPTS * FIN * 2);
  float* sq   = F + 0;                   // 4096
  int*   m1   = (int*)(F + 4096);        // 4096
  float* dkm  = F + 8192;                // 4096
  float* d1v  = F + 16384;               // 12288
  float* Wh   = F + 32768;               // 262144
  float* tmv  = F + 298248;              // 3
  float* Spart = F + 691712;             // 16384
  float* Vpart = F + 708096;             // 1048576
  __hip_bfloat16* WhbT = (__hip_bfloat16*)(F + 1756672); // 131072 floats
  float* G = F + 1900544;
  float* bvA    = G + 0;     // 64
  int*   biA    = (int*)(G + 64);
  float* bvB    = G + 128;
  int*   biB    = (int*)(G + 192);
  int*   b1s    = (int*)(G + 256);
  float* dcpart = G + 320;   // 64
  float* tmpart = G + 384;   // 192
  float* kvp    = G + 576;   // 64
  int*   kip    = (int*)(G + 640);
  float* pcA    = G + 704;   // 192
  float* pcB    = G + 896;   // 192
  float* psA    = G + 1088;  // 98304
  float* psB    = G + 99392; // 98304

  k_prep<<<NPTS / 4, 256, 0, stream>>>(h, W, xb, sq, m1, Wh);
  k_tr<<<16, 256, 0, stream>>>(Wh, WhbT);
  k_gram2<<<528, 256, 0, stream>>>(xb, sq, m1);

  k_fp0<<<64, 512, 0, stream>>>(h, m1, t2, dkm, bvA, biA, dcpart, tmpart, kvp, kip);
  k_fp1<<<64, 512, 0, stream>>>(h, dkm, bvA, biA, bvB, biB, b1s);
  k_lloyd0<<<64, 512, 0, stream>>>(h, sq, bvB, biB, b1s, psA, pcA);
  float* pin = psA; float* cin = pcA; float* pout = psB; float* cout = pcB;
  for (int it = 1; it < 10; ++it) {
    k_lloyd<<<64, 512, 0, stream>>>(h, sq, pin, cin, pout, cout);
    float* tp = pin; pin = pout; pout = tp;
    float* tc = cin; cin = cout; cout = tc;
  }
  k_fin<<<64, 512, 0, stream>>>(h, sq, pin, cin, dcpart, tmpart, kvp, kip, Wh, d1v, tmv, out);

  k_mainA<<<256, 256, 0, stream>>>(t2, WhbT, d1v, tmv, Vpart, Spart);
  k_comb<<<1024, 256, 0, stream>>>(Vpart, Spart, d1v, tmv, out);
}

// Round 6
// 224.764 us; speedup vs baseline: 1.6020x; 1.1330x over previous
//
#include <hip/hip_runtime.h>
#include <hip/hip_bf16.h>
#include <math.h>

#define NPTS 4096
#define FIN 512
#define FOUT 64

typedef __attribute__((ext_vector_type(8))) short bf16x8;
typedef __attribute__((ext_vector_type(4))) float f32x4;

static __device__ __forceinline__ unsigned short bfbits(float x) {
  __hip_bfloat16 b = __float2bfloat16(x);
  return *reinterpret_cast<unsigned short*>(&b);
}

static __device__ __forceinline__ float wsum64(float v) {
  #pragma unroll
  for (int mm = 1; mm < 64; mm <<= 1) v += __shfl_xor(v, mm);
  return v;
}

// ---------------- prep: bf16 copy of h, row norms, init m1, Wh = h@W ----------------
__global__ __launch_bounds__(256) void k_prep(const float* __restrict__ h,
    const float* __restrict__ W, __hip_bfloat16* __restrict__ xb,
    float* __restrict__ sq, int* __restrict__ m1, float* __restrict__ Wh) {
  __shared__ float hs[4][512];
  int t = threadIdx.x, lane = t & 63, wid = t >> 6;
  int row = blockIdx.x * 4 + wid;
  const float4* hr = (const float4*)(h + (size_t)row * FIN);
  float4 a = hr[lane], b = hr[64 + lane];
  ushort4 pa = { bfbits(a.x), bfbits(a.y), bfbits(a.z), bfbits(a.w) };
  ushort4 pb = { bfbits(b.x), bfbits(b.y), bfbits(b.z), bfbits(b.w) };
  *(ushort4*)(xb + (size_t)row * FIN + 4 * lane) = pa;
  *(ushort4*)(xb + (size_t)row * FIN + 256 + 4 * lane) = pb;
  float s = a.x*a.x + a.y*a.y + a.z*a.z + a.w*a.w
          + b.x*b.x + b.y*b.y + b.z*b.z + b.w*b.w;
  s = wsum64(s);
  if (lane == 0) { sq[row] = s; m1[row] = 0x7F800000; }
  *(float4*)&hs[wid][4 * lane] = a;
  *(float4*)&hs[wid][256 + 4 * lane] = b;
  __syncthreads();
  float a0 = 0.f, a1 = 0.f, a2 = 0.f, a3 = 0.f;
  #pragma unroll 2
  for (int k = 0; k < 512; k += 4) {
    a0 = fmaf(hs[wid][k + 0], W[(k + 0) * FOUT + lane], a0);
    a1 = fmaf(hs[wid][k + 1], W[(k + 1) * FOUT + lane], a1);
    a2 = fmaf(hs[wid][k + 2], W[(k + 2) * FOUT + lane], a2);
    a3 = fmaf(hs[wid][k + 3], W[(k + 3) * FOUT + lane], a3);
  }
  Wh[(size_t)row * FOUT + lane] = (a0 + a1) + (a2 + a3);
}

// ---------------- transpose Wh -> WhbT (bf16, [64][4096]) ----------------
__global__ __launch_bounds__(256) void k_tr(const float* __restrict__ Wh,
    __hip_bfloat16* __restrict__ WhbT) {
  __shared__ __hip_bfloat16 tT[64][264];
  int t = threadIdx.x;
  int kbase = blockIdx.x * 256;
  for (int rep = 0; rep < 64; ++rep) {
    int idx = t + rep * 256;
    int k = idx >> 6, n = idx & 63;
    tT[n][k] = __float2bfloat16(Wh[(size_t)(kbase + k) * FOUT + n]);
  }
  __syncthreads();
  int n = t >> 2, kq = t & 3;
  #pragma unroll
  for (int rep = 0; rep < 8; ++rep) {
    int kk = kq * 64 + rep * 8;
    bf16x8 v = *(const bf16x8*)&tT[n][kk];
    *(bf16x8*)(WhbT + (size_t)n * NPTS + kbase + kk) = v;
  }
}

// ---------------- Gram + per-row NN-min: LDS-staged MFMA, triangular grid ----------------
__global__ __launch_bounds__(256) void k_gram2(const __hip_bfloat16* __restrict__ xb,
    const float* __restrict__ sq, int* __restrict__ m1) {
  int b = blockIdx.x, I = 0;
  while (b >= 32 - I) { b -= 32 - I; ++I; }
  int J = I + b;
  int tid = threadIdx.x, lane = tid & 63, wid = tid >> 6;

  __shared__ __align__(16) __hip_bfloat16 As[128 * 64];
  __shared__ __align__(16) __hip_bfloat16 Bs[128 * 64];

  int R0 = I * 128, C0 = J * 128;
  int rowBase = (wid >> 1) * 64;
  int colBase = (wid & 1) * 64;
  int lrow = lane & 15, hi = lane >> 4, rsub = hi * 4;

  f32x4 acc[4][4];
  #pragma unroll
  for (int p = 0; p < 4; ++p)
    #pragma unroll
    for (int q = 0; q < 4; ++q)
      acc[p][q] = (f32x4){0.f, 0.f, 0.f, 0.f};

  int srow = lane >> 3;
  int scol = ((lane & 7) ^ srow) * 8;
  const __hip_bfloat16* gA = xb + (size_t)(R0 + wid * 32 + srow) * FIN + scol;
  const __hip_bfloat16* gB = xb + (size_t)(C0 + wid * 32 + srow) * FIN + scol;
  char* lA = (char*)As + wid * 4096;
  char* lB = (char*)Bs + wid * 4096;
  int rdswz = (lrow & 7) << 4;

  for (int kt = 0; kt < 8; ++kt) {
    int K0 = kt * 64;
    #pragma unroll
    for (int j = 0; j < 4; ++j) {
      __builtin_amdgcn_global_load_lds(
          (const __attribute__((address_space(1))) unsigned int*)(gA + (size_t)(8 * j) * FIN + K0),
          (__attribute__((address_space(3))) unsigned int*)(lA + j * 1024), 16, 0, 0);
      __builtin_amdgcn_global_load_lds(
          (const __attribute__((address_space(1))) unsigned int*)(gB + (size_t)(8 * j) * FIN + K0),
          (__attribute__((address_space(3))) unsigned int*)(lB + j * 1024), 16, 0, 0);
    }
    __syncthreads();
    #pragma unroll
    for (int s = 0; s < 2; ++s) {
      int k0b = s * 64;
      bf16x8 av[4], bw[4];
      #pragma unroll
      for (int f = 0; f < 4; ++f) {
        int arow = rowBase + f * 16 + lrow;
        av[f] = *(const bf16x8*)((const char*)As + arow * 128 + ((k0b + hi * 16) ^ rdswz));
        int brow = colBase + f * 16 + lrow;
        bw[f] = *(const bf16x8*)((const char*)Bs + brow * 128 + ((k0b + hi * 16) ^ rdswz));
      }
      #pragma unroll
      for (int fi = 0; fi < 4; ++fi)
        #pragma unroll
        for (int fj = 0; fj < 4; ++fj)
          acc[fi][fj] = __builtin_amdgcn_mfma_f32_16x16x32_bf16(av[fi], bw[fj], acc[fi][fj], 0, 0, 0);
    }
    __syncthreads();
  }

  int rowBaseG = R0 + rowBase, colBaseG = C0 + colBase;
  float sqr[16], sqc4[4];
  #pragma unroll
  for (int fi = 0; fi < 4; ++fi)
    #pragma unroll
    for (int rg = 0; rg < 4; ++rg)
      sqr[fi * 4 + rg] = sq[rowBaseG + fi * 16 + rsub + rg];
  #pragma unroll
  for (int fj = 0; fj < 4; ++fj) sqc4[fj] = sq[colBaseG + fj * 16 + lrow];

  float rmin[16], cmin[4];
  #pragma unroll
  for (int q = 0; q < 16; ++q) rmin[q] = INFINITY;
  #pragma unroll
  for (int q = 0; q < 4; ++q) cmin[q] = INFINITY;

  #pragma unroll
  for (int fi = 0; fi < 4; ++fi)
    #pragma unroll
    for (int fj = 0; fj < 4; ++fj)
      #pragma unroll
      for (int rg = 0; rg < 4; ++rg) {
        int r = rowBaseG + fi * 16 + rsub + rg;
        int c = colBaseG + fj * 16 + lrow;
        float d2 = sqr[fi * 4 + rg] + sqc4[fj] - 2.f * acc[fi][fj][rg];
        if (r == c) d2 = INFINITY;
        rmin[fi * 4 + rg] = fminf(rmin[fi * 4 + rg], d2);
        cmin[fj] = fminf(cmin[fj], d2);
      }

  #pragma unroll
  for (int mm = 1; mm < 16; mm <<= 1) {
    #pragma unroll
    for (int q = 0; q < 16; ++q) rmin[q] = fminf(rmin[q], __shfl_xor(rmin[q], mm));
  }
  if ((lane & 15) == 0) {
    #pragma unroll
    for (int q = 0; q < 16; ++q) {
      int r = rowBaseG + (q >> 2) * 16 + rsub + (q & 3);
      atomicMin(&m1[r], __float_as_int(rmin[q]));
    }
  }
  if (I != J) {
    #pragma unroll
    for (int mm = 16; mm < 64; mm <<= 1) {
      #pragma unroll
      for (int q = 0; q < 4; ++q) cmin[q] = fminf(cmin[q], __shfl_xor(cmin[q], mm));
    }
    if ((lane >> 4) == 0) {
      #pragma unroll
      for (int q = 0; q < 4; ++q)
        atomicMin(&m1[colBaseG + q * 16 + lane], __float_as_int(cmin[q]));
    }
  }
}

// ---------------- row-block loader: 8 rows x 8 dims into regs ----------------
__device__ __forceinline__ void load_rows(const float* __restrict__ h, int rbase,
    int lane, float x[8][8]) {
  #pragma unroll
  for (int r = 0; r < 8; ++r) {
    const float4* xr = (const float4*)(h + (size_t)(rbase + r) * FIN);
    float4 u0 = xr[2 * lane], u1 = xr[2 * lane + 1];
    x[r][0]=u0.x; x[r][1]=u0.y; x[r][2]=u0.z; x[r][3]=u0.w;
    x[r][4]=u1.x; x[r][5]=u1.y; x[r][6]=u1.z; x[r][7]=u1.w;
  }
}

// ---------------- farthest-point pass A + side partials (dc/tm/kstar) ----------------
__global__ __launch_bounds__(512) void k_fp0(const float* __restrict__ h,
    const float* __restrict__ sq, const int* __restrict__ m1, const float* __restrict__ t2,
    float* __restrict__ dkm, float* __restrict__ bvA, int* __restrict__ biA,
    float* __restrict__ dcpart, float* __restrict__ tmpart,
    float* __restrict__ kvp, int* __restrict__ kip) {
  int t = threadIdx.x, lane = t & 63, wid = t >> 6, b = blockIdx.x;
  __shared__ float rv[8]; __shared__ int ri[8];
  float cr[8];
  {
    const float4* cp = (const float4*)h;
    float4 u0 = cp[2 * lane], u1 = cp[2 * lane + 1];
    cr[0]=u0.x;cr[1]=u0.y;cr[2]=u0.z;cr[3]=u0.w;cr[4]=u1.x;cr[5]=u1.y;cr[6]=u1.z;cr[7]=u1.w;
  }
  float s0 = 0.f;
  #pragma unroll
  for (int q = 0; q < 8; ++q) s0 = fmaf(cr[q], cr[q], s0);
  float sqc0 = wsum64(s0);
  int rbase = b * 64 + wid * 8;
  float x[8][8];
  load_rows(h, rbase, lane, x);
  float dd[8];
  #pragma unroll
  for (int r = 0; r < 8; ++r) dd[r] = 0.f;
  #pragma unroll
  for (int r = 0; r < 8; ++r)
    #pragma unroll
    for (int q = 0; q < 8; ++q) dd[r] = fmaf(x[r][q], cr[q], dd[r]);
  #pragma unroll
  for (int mm = 1; mm < 64; mm <<= 1) {
    #pragma unroll
    for (int r = 0; r < 8; ++r) dd[r] += __shfl_xor(dd[r], mm);
  }
  float bv = -1.f; int bi = 0;
  #pragma unroll
  for (int r = 0; r < 8; ++r) {
    int row = rbase + r;
    float d = sq[row] + sqc0 - 2.f * dd[r];
    if (lane == 0) dkm[row] = d;
    if (d > bv) { bv = d; bi = row; }
  }
  if (lane == 0) { rv[wid] = bv; ri[wid] = bi; }
  // side partials
  if (wid == 1) {
    #pragma unroll
    for (int c = 0; c < 3; ++c) {
      float m = fabsf(t2[c * NPTS + b * 64 + lane]);
      #pragma unroll
      for (int mm = 1; mm < 64; mm <<= 1) m = fmaxf(m, __shfl_xor(m, mm));
      if (lane == 0) tmpart[b * 3 + c] = m;
    }
  } else if (wid == 2) {
    int k = b * 64 + lane;
    float v = t2[k] + t2[NPTS + k] + t2[2 * NPTS + k];
    int ki = k;
    #pragma unroll
    for (int mm = 1; mm < 64; mm <<= 1) {
      float ov = __shfl_xor(v, mm); int oi = __shfl_xor(ki, mm);
      if (ov < v || (ov == v && oi < ki)) { v = ov; ki = oi; }
    }
    if (lane == 0) { kvp[b] = v; kip[b] = ki; }
  } else if (wid == 3) {
    float v = sqrtf(fmaxf(__int_as_float(m1[b * 64 + lane]), 0.f));
    v = wsum64(v);
    if (lane == 0) dcpart[b] = v;
  }
  __syncthreads();
  if (t == 0) {
    float vv = rv[0]; int ii = ri[0];
    for (int w = 1; w < 8; ++w)
      if (rv[w] > vv || (rv[w] == vv && ri[w] < ii)) { vv = rv[w]; ii = ri[w]; }
    bvA[b] = vv; biA[b] = ii;
  }
}

// ---------------- farthest-point pass B ----------------
__global__ __launch_bounds__(512) void k_fp1(const float* __restrict__ h,
    const float* __restrict__ sq,
    float* __restrict__ dkm, const float* __restrict__ bvA, const int* __restrict__ biA,
    float* __restrict__ bvB, int* __restrict__ biB, int* __restrict__ b1s) {
  int t = threadIdx.x, lane = t & 63, wid = t >> 6, b = blockIdx.x;
  __shared__ float rv[8]; __shared__ int ri[8]; __shared__ int sb1;
  if (wid == 0) {
    float v = bvA[lane]; int i = biA[lane];
    #pragma unroll
    for (int mm = 1; mm < 64; mm <<= 1) {
      float ov = __shfl_xor(v, mm); int oi = __shfl_xor(i, mm);
      if (ov > v || (ov == v && oi < i)) { v = ov; i = oi; }
    }
    if (lane == 0) sb1 = i;
  }
  __syncthreads();
  int b1 = sb1;
  if (b == 0 && t == 0) b1s[0] = b1;
  float cr[8];
  {
    const float4* cp = (const float4*)(h + (size_t)b1 * FIN);
    float4 u0 = cp[2 * lane], u1 = cp[2 * lane + 1];
    cr[0]=u0.x;cr[1]=u0.y;cr[2]=u0.z;cr[3]=u0.w;cr[4]=u1.x;cr[5]=u1.y;cr[6]=u1.z;cr[7]=u1.w;
  }
  float s0 = 0.f;
  #pragma unroll
  for (int q = 0; q < 8; ++q) s0 = fmaf(cr[q], cr[q], s0);
  float sqc0 = wsum64(s0);
  int rbase = b * 64 + wid * 8;
  float x[8][8];
  load_rows(h, rbase, lane, x);
  float dd[8];
  #pragma unroll
  for (int r = 0; r < 8; ++r) dd[r] = 0.f;
  #pragma unroll
  for (int r = 0; r < 8; ++r)
    #pragma unroll
    for (int q = 0; q < 8; ++q) dd[r] = fmaf(x[r][q], cr[q], dd[r]);
  #pragma unroll
  for (int mm = 1; mm < 64; mm <<= 1) {
    #pragma unroll
    for (int r = 0; r < 8; ++r) dd[r] += __shfl_xor(dd[r], mm);
  }
  float bv = -1.f; int bi = 0;
  #pragma unroll
  for (int r = 0; r < 8; ++r) {
    int row = rbase + r;
    float d = sq[row] + sqc0 - 2.f * dd[r];
    d = fminf(d, dkm[row]);
    if (lane == 0) dkm[row] = d;
    if (d > bv) { bv = d; bi = row; }
  }
  if (lane == 0) { rv[wid] = bv; ri[wid] = bi; }
  __syncthreads();
  if (t == 0) {
    float vv = rv[0]; int ii = ri[0];
    for (int w = 1; w < 8; ++w)
      if (rv[w] > vv || (rv[w] == vv && ri[w] < ii)) { vv = rv[w]; ii = ri[w]; }
    bvB[b] = vv; biB[b] = ii;
  }
}

// ---------------- shared Lloyd assign (8 rows/wave, batched reduces) ----------------
__device__ __forceinline__ void lloyd_assign(const float* __restrict__ h,
    const float* __restrict__ sq, const float* cents, float* wsum, float* wcnt,
    float* __restrict__ psOut, float* __restrict__ pcOut) {
  int t = threadIdx.x, lane = t & 63, wid = t >> 6, b = blockIdx.x;
  float c0r[8], c1r[8], c2r[8];
  {
    float4 u;
    u = *(const float4*)&cents[8 * lane];          c0r[0]=u.x;c0r[1]=u.y;c0r[2]=u.z;c0r[3]=u.w;
    u = *(const float4*)&cents[8 * lane + 4];      c0r[4]=u.x;c0r[5]=u.y;c0r[6]=u.z;c0r[7]=u.w;
    u = *(const float4*)&cents[512 + 8 * lane];    c1r[0]=u.x;c1r[1]=u.y;c1r[2]=u.z;c1r[3]=u.w;
    u = *(const float4*)&cents[512 + 8 * lane + 4];c1r[4]=u.x;c1r[5]=u.y;c1r[6]=u.z;c1r[7]=u.w;
    u = *(const float4*)&cents[1024 + 8 * lane];   c2r[0]=u.x;c2r[1]=u.y;c2r[2]=u.z;c2r[3]=u.w;
    u = *(const float4*)&cents[1024 + 8*lane + 4]; c2r[4]=u.x;c2r[5]=u.y;c2r[6]=u.z;c2r[7]=u.w;
  }
  float s0 = 0.f, s1 = 0.f, s2 = 0.f;
  #pragma unroll
  for (int q = 0; q < 8; ++q) {
    s0 = fmaf(c0r[q], c0r[q], s0); s1 = fmaf(c1r[q], c1r[q], s1); s2 = fmaf(c2r[q], c2r[q], s2);
  }
  #pragma unroll
  for (int mm = 1; mm < 64; mm <<= 1) {
    s0 += __shfl_xor(s0, mm); s1 += __shfl_xor(s1, mm); s2 += __shfl_xor(s2, mm);
  }
  float sqc0 = s0, sqc1 = s1, sqc2 = s2;

  int rbase = b * 64 + wid * 8;
  float x[8][8];
  load_rows(h, rbase, lane, x);
  float d[8][3];
  #pragma unroll
  for (int r = 0; r < 8; ++r) { d[r][0] = 0.f; d[r][1] = 0.f; d[r][2] = 0.f; }
  #pragma unroll
  for (int r = 0; r < 8; ++r)
    #pragma unroll
    for (int q = 0; q < 8; ++q) {
      d[r][0] = fmaf(x[r][q], c0r[q], d[r][0]);
      d[r][1] = fmaf(x[r][q], c1r[q], d[r][1]);
      d[r][2] = fmaf(x[r][q], c2r[q], d[r][2]);
    }
  #pragma unroll
  for (int mm = 1; mm < 64; mm <<= 1) {
    #pragma unroll
    for (int r = 0; r < 8; ++r) {
      d[r][0] += __shfl_xor(d[r][0], mm);
      d[r][1] += __shfl_xor(d[r][1], mm);
      d[r][2] += __shfl_xor(d[r][2], mm);
    }
  }
  float ps[3][8];
  #pragma unroll
  for (int c = 0; c < 3; ++c)
    #pragma unroll
    for (int q = 0; q < 8; ++q) ps[c][q] = 0.f;
  float cnt0 = 0.f, cnt1 = 0.f, cnt2 = 0.f;
  #pragma unroll
  for (int r = 0; r < 8; ++r) {
    float sr = sq[rbase + r];
    float e0 = sr + sqc0 - 2.f * d[r][0];
    float e1 = sr + sqc1 - 2.f * d[r][1];
    float e2 = sr + sqc2 - 2.f * d[r][2];
    int bc = 0; float bd = e0;
    if (e1 < bd) { bd = e1; bc = 1; }
    if (e2 < bd) { bd = e2; bc = 2; }
    float f0 = bc == 0 ? 1.f : 0.f, f1 = bc == 1 ? 1.f : 0.f, f2 = bc == 2 ? 1.f : 0.f;
    #pragma unroll
    for (int q = 0; q < 8; ++q) {
      ps[0][q] = fmaf(f0, x[r][q], ps[0][q]);
      ps[1][q] = fmaf(f1, x[r][q], ps[1][q]);
      ps[2][q] = fmaf(f2, x[r][q], ps[2][q]);
    }
    cnt0 += f0; cnt1 += f1; cnt2 += f2;
  }
  #pragma unroll
  for (int c = 0; c < 3; ++c) {
    *(float4*)&wsum[wid * 1536 + c * 512 + 8 * lane]     = make_float4(ps[c][0], ps[c][1], ps[c][2], ps[c][3]);
    *(float4*)&wsum[wid * 1536 + c * 512 + 8 * lane + 4] = make_float4(ps[c][4], ps[c][5], ps[c][6], ps[c][7]);
  }
  if (lane == 0) { wcnt[wid * 3 + 0] = cnt0; wcnt[wid * 3 + 1] = cnt1; wcnt[wid * 3 + 2] = cnt2; }
  __syncthreads();
  for (int idx = t; idx < 1536; idx += 512) {
    float s = ((wsum[0 * 1536 + idx] + wsum[1 * 1536 + idx]) + (wsum[2 * 1536 + idx] + wsum[3 * 1536 + idx]))
            + ((wsum[4 * 1536 + idx] + wsum[5 * 1536 + idx]) + (wsum[6 * 1536 + idx] + wsum[7 * 1536 + idx]));
    psOut[(size_t)b * 1536 + idx] = s;
  }
  if (t < 3) {
    float s = 0.f;
    for (int w = 0; w < 8; ++w) s += wcnt[w * 3 + t];
    pcOut[t * 64 + b] = s;   // layout [c][64]
  }
}

// ---------------- Lloyd iter 0: init centers from (0, b1, b2), assign ----------------
__global__ __launch_bounds__(512) void k_lloyd0(const float* __restrict__ h,
    const float* __restrict__ sq, const float* __restrict__ bvB, const int* __restrict__ biB,
    const int* __restrict__ b1s, float* __restrict__ psOut, float* __restrict__ pcOut) {
  __shared__ float cents[1536];
  __shared__ float wsum[8 * 1536];
  __shared__ float wcnt[24];
  __shared__ int sb2;
  int t = threadIdx.x, lane = t & 63, wid = t >> 6;
  if (wid == 0) {
    float v = bvB[lane]; int i = biB[lane];
    #pragma unroll
    for (int mm = 1; mm < 64; mm <<= 1) {
      float ov = __shfl_xor(v, mm); int oi = __shfl_xor(i, mm);
      if (ov > v || (ov == v && oi < i)) { v = ov; i = oi; }
    }
    if (lane == 0) sb2 = i;
  }
  __syncthreads();
  int b1 = b1s[0], b2 = sb2;
  cents[t]        = h[t];
  cents[512 + t]  = h[(size_t)b1 * FIN + t];
  cents[1024 + t] = h[(size_t)b2 * FIN + t];
  __syncthreads();
  lloyd_assign(h, sq, cents, wsum, wcnt, psOut, pcOut);
}

// ---------------- Lloyd iter k: f32x4 reduce -> centers, assign ----------------
__global__ __launch_bounds__(512) void k_lloyd(const float* __restrict__ h,
    const float* __restrict__ sq, const float* __restrict__ psIn, const float* __restrict__ pcIn,
    float* __restrict__ psOut, float* __restrict__ pcOut) {
  __shared__ float cents[1536];
  __shared__ float wsum[8 * 1536];
  __shared__ float wcnt[24];
  __shared__ float cntS[3];
  int t = threadIdx.x;
  if (t < 192) {
    float v = pcIn[t];           // [c*64+b], wave c holds c's 64 partials
    v = wsum64(v);
    if ((t & 63) == 0) cntS[t >> 6] = v;
  }
  __syncthreads();
  if (t < 384) {
    const f32x4* P = (const f32x4*)psIn;
    f32x4 a0 = {0,0,0,0}, a1 = {0,0,0,0}, a2 = {0,0,0,0}, a3 = {0,0,0,0};
    #pragma unroll 4
    for (int bq = 0; bq < 64; bq += 4) {
      a0 += P[(bq + 0) * 384 + t];
      a1 += P[(bq + 1) * 384 + t];
      a2 += P[(bq + 2) * 384 + t];
      a3 += P[(bq + 3) * 384 + t];
    }
    f32x4 s = (a0 + a1) + (a2 + a3);
    float cden = fmaxf(cntS[t >> 7], 1.f);
    f32x4 res;
    res[0] = s[0] / cden; res[1] = s[1] / cden; res[2] = s[2] / cden; res[3] = s[3] / cden;
    *(f32x4*)&cents[4 * t] = res;
  }
  __syncthreads();
  lloyd_assign(h, sq, cents, wsum, wcnt, psOut, pcOut);
}

// ---------------- finalize: centers, dc, d1val, tm/kstar tail ----------------
__global__ __launch_bounds__(512) void k_fin(const float* __restrict__ h,
    const float* __restrict__ sq, const float* __restrict__ psIn, const float* __restrict__ pcIn,
    const float* __restrict__ dcpart, const float* __restrict__ tmpart,
    const float* __restrict__ kvp, const int* __restrict__ kip,
    const float* __restrict__ Wh, float* __restrict__ d1v,
    float* __restrict__ tmv, float* __restrict__ out) {
  __shared__ float cents[1536];
  __shared__ float cntS[3];
  __shared__ int skstar;
  int t = threadIdx.x, lane = t & 63, wid = t >> 6, b = blockIdx.x;
  if (t < 192) {
    float v = pcIn[t];
    v = wsum64(v);
    if ((t & 63) == 0) cntS[t >> 6] = v;
  }
  __syncthreads();
  if (t < 384) {
    const f32x4* P = (const f32x4*)psIn;
    f32x4 a0 = {0,0,0,0}, a1 = {0,0,0,0}, a2 = {0,0,0,0}, a3 = {0,0,0,0};
    #pragma unroll 4
    for (int bq = 0; bq < 64; bq += 4) {
      a0 += P[(bq + 0) * 384 + t];
      a1 += P[(bq + 1) * 384 + t];
      a2 += P[(bq + 2) * 384 + t];
      a3 += P[(bq + 3) * 384 + t];
    }
    f32x4 s = (a0 + a1) + (a2 + a3);
    float cden = fmaxf(cntS[t >> 7], 1.f);
    f32x4 res;
    res[0] = s[0] / cden; res[1] = s[1] / cden; res[2] = s[2] / cden; res[3] = s[3] / cden;
    *(f32x4*)&cents[4 * t] = res;
  }
  __syncthreads();
  float c0r[8], c1r[8], c2r[8];
  {
    float4 u;
    u = *(const float4*)&cents[8 * lane];          c0r[0]=u.x;c0r[1]=u.y;c0r[2]=u.z;c0r[3]=u.w;
    u = *(const float4*)&cents[8 * lane + 4];      c0r[4]=u.x;c0r[5]=u.y;c0r[6]=u.z;c0r[7]=u.w;
    u = *(const float4*)&cents[512 + 8 * lane];    c1r[0]=u.x;c1r[1]=u.y;c1r[2]=u.z;c1r[3]=u.w;
    u = *(const float4*)&cents[512 + 8 * lane + 4];c1r[4]=u.x;c1r[5]=u.y;c1r[6]=u.z;c1r[7]=u.w;
    u = *(const float4*)&cents[1024 + 8 * lane];   c2r[0]=u.x;c2r[1]=u.y;c2r[2]=u.z;c2r[3]=u.w;
    u = *(const float4*)&cents[1024 + 8*lane + 4]; c2r[4]=u.x;c2r[5]=u.y;c2r[6]=u.z;c2r[7]=u.w;
  }
  float s0 = 0.f, s1 = 0.f, s2 = 0.f;
  #pragma unroll
  for (int q = 0; q < 8; ++q) {
    s0 = fmaf(c0r[q], c0r[q], s0); s1 = fmaf(c1r[q], c1r[q], s1); s2 = fmaf(c2r[q], c2r[q], s2);
  }
  float dcv = dcpart[lane];
  #pragma unroll
  for (int mm = 1; mm < 64; mm <<= 1) {
    s0 += __shfl_xor(s0, mm); s1 += __shfl_xor(s1, mm); s2 += __shfl_xor(s2, mm);
    dcv += __shfl_xor(dcv, mm);
  }
  float sqc0 = s0, sqc1 = s1, sqc2 = s2;
  dcv *= (1.f / (float)NPTS);

  int rbase = b * 64 + wid * 8;
  float x[8][8];
  load_rows(h, rbase, lane, x);
  float d[8][3];
  #pragma unroll
  for (int r = 0; r < 8; ++r) { d[r][0] = 0.f; d[r][1] = 0.f; d[r][2] = 0.f; }
  #pragma unroll
  for (int r = 0; r < 8; ++r)
    #pragma unroll
    for (int q = 0; q < 8; ++q) {
      d[r][0] = fmaf(x[r][q], c0r[q], d[r][0]);
      d[r][1] = fmaf(x[r][q], c1r[q], d[r][1]);
      d[r][2] = fmaf(x[r][q], c2r[q], d[r][2]);
    }
  #pragma unroll
  for (int mm = 1; mm < 64; mm <<= 1) {
    #pragma unroll
    for (int r = 0; r < 8; ++r) {
      d[r][0] += __shfl_xor(d[r][0], mm);
      d[r][1] += __shfl_xor(d[r][1], mm);
      d[r][2] += __shfl_xor(d[r][2], mm);
    }
  }
  if (lane == 0) {
    #pragma unroll
    for (int r = 0; r < 8; ++r) {
      int row = rbase + r;
      float sr = sq[row];
      float q0 = sqrtf(fmaxf(sr + sqc0 - 2.f * d[r][0], 0.f));
      float q1 = sqrtf(fmaxf(sr + sqc1 - 2.f * d[r][1], 0.f));
      float q2 = sqrtf(fmaxf(sr + sqc2 - 2.f * d[r][2], 0.f));
      float nr = q1;
      d1v[row * 3 + 0] = (q0 != 0.f) ? (dcv * nr / (q0 * q0)) : 0.f;
      d1v[row * 3 + 1] = (q1 != 0.f) ? (dcv * nr / (q1 * q1)) : 0.f;
      d1v[row * 3 + 2] = (q2 != 0.f) ? (dcv * nr / (q2 * q2)) : 0.f;
    }
  }
  if (b == 0) {
    if (t < 3) {
      float m = 0.f;
      for (int q = 0; q < 64; ++q) m = fmaxf(m, tmpart[q * 3 + t]);
      tmv[t] = m;
    }
    if (wid == 0) {
      float v = kvp[lane]; int i = kip[lane];
      #pragma unroll
      for (int mm = 1; mm < 64; mm <<= 1) {
        float ov = __shfl_xor(v, mm); int oi = __shfl_xor(i, mm);
        if (ov < v || (ov == v && oi < i)) { v = ov; i = oi; }
      }
      if (lane == 0) skstar = i;
    }
    __syncthreads();
    int kstar = skstar;
    if (t < 192) {
      int c = t >> 6, j = t & 63;
      float wv = Wh[(size_t)kstar * FOUT + j];
      out[(size_t)(NPTS + c) * FOUT + j] = wv > 0.f ? wv : expm1f(wv);
    }
  }
}

// ---------------- fused MFMA softmax-numerator @ Wh: 512 thr, waves split K-half ----------------
__global__ __launch_bounds__(512) void k_mainA(const float* __restrict__ t2,
    const __hip_bfloat16* __restrict__ WhbT, const float* __restrict__ d1v,
    const float* __restrict__ tm, float* __restrict__ Vpart, float* __restrict__ Spart) {
  int t = threadIdx.x, lane = t & 63, wid = t >> 6;
  int rb = blockIdx.x & 63, ks = blockIdx.x >> 6;
  int R0 = rb * 64, K0 = ks * 1024;
  __shared__ float t2s[3 * 1024];
  __shared__ float VcS[4][16][68];
  __shared__ float SpS[4][2][16];
  for (int idx = t; idx < 3072; idx += 512) {
    int c = idx >> 10, kl = idx & 1023;
    t2s[idx] = t2[c * NPTS + K0 + kl];
  }
  __syncthreads();
  int r = lane & 15, hi = lane >> 4;
  int rg = wid & 3, kh = wid >> 2;
  int row_g = R0 + rg * 16 + r;
  float a0 = d1v[row_g * 3 + 0], a1 = d1v[row_g * 3 + 1], a2 = d1v[row_g * 3 + 2];
  float M = fmaf(fabsf(a2), tm[2], fmaf(fabsf(a1), tm[1], fabsf(a0) * tm[0]));
  f32x4 acc[4];
  #pragma unroll
  for (int fn = 0; fn < 4; ++fn) acc[fn] = (f32x4){0.f, 0.f, 0.f, 0.f};
  float Sp = 0.f;
  const __hip_bfloat16* bwB[4];
  #pragma unroll
  for (int fn = 0; fn < 4; ++fn)
    bwB[fn] = WhbT + (size_t)(fn * 16 + r) * NPTS + K0 + kh * 512 + hi * 8;

  for (int kst = 0; kst < 16; ++kst) {
    int kb = kh * 512 + kst * 32 + hi * 8;
    f32x4 c0a = *(const f32x4*)&t2s[kb],        c0b = *(const f32x4*)&t2s[kb + 4];
    f32x4 c1a = *(const f32x4*)&t2s[1024 + kb], c1b = *(const f32x4*)&t2s[1024 + kb + 4];
    f32x4 c2a = *(const f32x4*)&t2s[2048 + kb], c2b = *(const f32x4*)&t2s[2048 + kb + 4];
    float pv[8];
    #pragma unroll
    for (int j = 0; j < 4; ++j) {
      float L  = fmaf(a0, c0a[j], fmaf(a1, c1a[j], fmaf(a2, c2a[j], -M)));
      pv[j] = __expf(L);
      float L2 = fmaf(a0, c0b[j], fmaf(a1, c1b[j], fmaf(a2, c2b[j], -M)));
      pv[4 + j] = __expf(L2);
    }
    Sp += ((pv[0] + pv[1]) + (pv[2] + pv[3])) + ((pv[4] + pv[5]) + (pv[6] + pv[7]));
    union { bf16x8 v; __hip_bfloat162 h2[4]; } pa;
    #pragma unroll
    for (int jj = 0; jj < 4; ++jj) {
      float2 f2; f2.x = pv[2 * jj]; f2.y = pv[2 * jj + 1];
      pa.h2[jj] = __float22bfloat162_rn(f2);
    }
    #pragma unroll
    for (int fn = 0; fn < 4; ++fn) {
      bf16x8 bw = *(const bf16x8*)(bwB[fn] + kst * 32);
      acc[fn] = __builtin_amdgcn_mfma_f32_16x16x32_bf16(pa.v, bw, acc[fn], 0, 0, 0);
    }
  }
  Sp += __shfl_xor(Sp, 16);
  Sp += __shfl_xor(Sp, 32);
  if (hi == 0) SpS[rg][kh][r] = Sp;
  if (kh == 0) {
    #pragma unroll
    for (int fn = 0; fn < 4; ++fn)
      #pragma unroll
      for (int q = 0; q < 4; ++q)
        VcS[rg][hi * 4 + q][fn * 16 + r] = acc[fn][q];
  }
  __syncthreads();
  if (kh == 1) {
    #pragma unroll
    for (int fn = 0; fn < 4; ++fn)
      #pragma unroll
      for (int q = 0; q < 4; ++q) {
        float v = VcS[rg][hi * 4 + q][fn * 16 + r] + acc[fn][q];
        Vpart[(size_t)ks * (NPTS * FOUT) + (size_t)(R0 + rg * 16 + hi * 4 + q) * FOUT + fn * 16 + r] = v;
      }
    if (hi == 0) Spart[row_g * 4 + ks] = SpS[rg][0][r] + SpS[rg][1][r];
  }
}

// ---------------- combine partials: divide, ELU ----------------
__global__ __launch_bounds__(256) void k_comb(const float* __restrict__ Vpart,
    const float* __restrict__ Spart, const float* __restrict__ d1v,
    const float* __restrict__ tm, float* __restrict__ out) {
  int gid = blockIdx.x * 256 + threadIdx.x;
  int row = gid >> 6;
  float V = (Vpart[gid] + Vpart[NPTS * FOUT + gid])
          + (Vpart[2 * NPTS * FOUT + gid] + Vpart[3 * NPTS * FOUT + gid]);
  float s = (Spart[row * 4 + 0] + Spart[row * 4 + 1]) + (Spart[row * 4 + 2] + Spart[row * 4 + 3]);
  float a0 = d1v[row * 3 + 0], a1 = d1v[row * 3 + 1], a2 = d1v[row * 3 + 2];
  float M = fmaf(fabsf(a2), tm[2], fmaf(fabsf(a1), tm[1], fabsf(a0) * tm[0]));
  s += 3.f * __expf(-M);
  float o = V / s;
  out[gid] = o > 0.f ? o : expm1f(o);
}

extern "C" void kernel_launch(void* const* d_in, const int* in_sizes, int n_in,
                              void* d_out, int out_size, void* d_ws, size_t ws_size,
                              hipStream_t stream) {
  const float* h  = (const float*)d_in[0];
  const float* W  = (const float*)d_in[2];
  const float* t2 = (const float*)d_in[5];
  float* out = (float*)d_out;

  char* ws = (char*)d_ws;
  __hip_bfloat16* xb = (__hip_bfloat16*)ws;
  float* F = (float*)(ws + (size_t)NPTS * FIN * 2);
  float* sq   = F + 0;                   // 4096
  int*   m1   = (int*)(F + 4096);        // 4096
  float* dkm  = F + 8192;                // 4096
  float* d1v  = F + 16384;               // 12288
  float* Wh   = F + 32768;               // 262144
  float* tmv  = F + 298248;              // 3
  float* Spart = F + 691712;             // 16384
  float* Vpart = F + 708096;             // 1048576
  __hip_bfloat16* WhbT = (__hip_bfloat16*)(F + 1756672); // 131072 floats
  float* G = F + 1900544;
  float* bvA    = G + 0;     // 64
  int*   biA    = (int*)(G + 64);
  float* bvB    = G + 128;
  int*   biB    = (int*)(G + 192);
  int*   b1s    = (int*)(G + 256);
  float* dcpart = G + 320;   // 64
  float* tmpart = G + 384;   // 192
  float* kvp    = G + 576;   // 64
  int*   kip    = (int*)(G + 640);
  float* pcA    = G + 704;   // 192 ([c][64])
  float* pcB    = G + 896;   // 192
  float* psA    = G + 1088;  // 98304
  float* psB    = G + 99392; // 98304

  k_prep<<<NPTS / 4, 256, 0, stream>>>(h, W, xb, sq, m1, Wh);
  k_tr<<<16, 256, 0, stream>>>(Wh, WhbT);
  k_gram2<<<528, 256, 0, stream>>>(xb, sq, m1);

  k_fp0<<<64, 512, 0, stream>>>(h, sq, m1, t2, dkm, bvA, biA, dcpart, tmpart, kvp, kip);
  k_fp1<<<64, 512, 0, stream>>>(h, sq, dkm, bvA, biA, bvB, biB, b1s);
  k_lloyd0<<<64, 512, 0, stream>>>(h, sq, bvB, biB, b1s, psA, pcA);
  float* pin = psA; float* cin = pcA; float* pout = psB; float* cout = pcB;
  for (int it = 1; it < 10; ++it) {
    k_lloyd<<<64, 512, 0, stream>>>(h, sq, pin, cin, pout, cout);
    float* tp = pin; pin = pout; pout = tp;
    float* tc = cin; cin = cout; cout = tc;
  }
  k_fin<<<64, 512, 0, stream>>>(h, sq, pin, cin, dcpart, tmpart, kvp, kip, Wh, d1v, tmv, out);

  k_mainA<<<256, 512, 0, stream>>>(t2, WhbT, d1v, tmv, Vpart, Spart);
  k_comb<<<1024, 256, 0, stream>>>(Vpart, Spart, d1v, tmv, out);
}